// Round 6
// baseline (1721.736 us; speedup 1.0000x reference)
//
#include <hip/hip_runtime.h>
#include <hip/hip_bf16.h>

// Problem constants (from reference)
#define N_NODES 50000
#define E_EDGES 800000
#define DIN_K   384
#define DH_N    256
#define EPSN    1e-5f

typedef unsigned short ushortT;
typedef __attribute__((ext_vector_type(4))) float f32x4;
typedef __attribute__((ext_vector_type(8))) short bf16x8;

static __device__ __forceinline__ float bf2f(unsigned short u)
{
    return __uint_as_float(((unsigned)u) << 16);
}
static __device__ __forceinline__ unsigned short f2bf(float f)
{
    unsigned u = __float_as_uint(f);
    unsigned r = (u + 0x7fffu + ((u >> 16) & 1u)) >> 16;   // round-nearest-even
    return (unsigned short)r;
}
static __device__ __forceinline__ unsigned pack2(float a, float b)
{
    return (unsigned)f2bf(a) | ((unsigned)f2bf(b) << 16);
}
static __device__ __forceinline__ void unpack8(uint4 u, float* f)
{
    f[0] = bf2f((ushortT)(u.x & 0xffff)); f[1] = bf2f((ushortT)(u.x >> 16));
    f[2] = bf2f((ushortT)(u.y & 0xffff)); f[3] = bf2f((ushortT)(u.y >> 16));
    f[4] = bf2f((ushortT)(u.z & 0xffff)); f[5] = bf2f((ushortT)(u.z >> 16));
    f[6] = bf2f((ushortT)(u.w & 0xffff)); f[7] = bf2f((ushortT)(u.w >> 16));
}

// ---------------------------------------------------------------------------
// edge_attr column sums (thread always hits column tid%32)
__global__ __launch_bounds__(256) void ea_accum_kernel(const float* __restrict__ ea,
                                                       float* __restrict__ accum, long total)
{
    long stride = (long)gridDim.x * blockDim.x;
    float local = 0.f;
    for (long i = (long)blockIdx.x * blockDim.x + threadIdx.x; i < total; i += stride)
        local += ea[i];
    __shared__ float red[256];
    red[threadIdx.x] = local;
    __syncthreads();
    if (threadIdx.x < 32) {
        float s = 0.f;
#pragma unroll
        for (int r = 0; r < 8; ++r) s += red[r * 32 + threadIdx.x];
        atomicAdd(&accum[threadIdx.x], s);
    }
}

// histogram of dst
__global__ void hist_kernel(const int* __restrict__ dst, int* __restrict__ counts, int E)
{
    int stride = gridDim.x * blockDim.x;
    for (int e = blockIdx.x * blockDim.x + threadIdx.x; e < E; e += stride)
        atomicAdd(&counts[dst[e]], 1);
}

// exclusive scan of counts -> offsets[N+1], single block
__global__ __launch_bounds__(1024) void scan_kernel(const int* __restrict__ counts,
                                                    int* __restrict__ offsets, int Nn)
{
    __shared__ int sdata[1024];
    __shared__ int run_s;
    int tid = threadIdx.x;
    if (tid == 0) run_s = 0;
    __syncthreads();
    for (int base2 = 0; base2 < Nn; base2 += 1024) {
        int i = base2 + tid;
        int v = (i < Nn) ? counts[i] : 0;
        sdata[tid] = v;
        __syncthreads();
        for (int off = 1; off < 1024; off <<= 1) {
            int t = (tid >= off) ? sdata[tid - off] : 0;
            __syncthreads();
            sdata[tid] += t;
            __syncthreads();
        }
        int run = run_s;
        if (i < Nn) offsets[i] = run + sdata[tid] - v;   // exclusive
        int tot = sdata[1023];
        __syncthreads();
        if (tid == 0) run_s = run + tot;
        __syncthreads();
    }
    if (tid == 0) offsets[Nn] = run_s;
}

// scatter edges into dst-sorted order
__global__ void scatter_kernel(const int* __restrict__ src, const int* __restrict__ dst,
                               const int* __restrict__ offsets, int* __restrict__ cursors,
                               int* __restrict__ s_src, int* __restrict__ s_dst,
                               int* __restrict__ s_eid, int E)
{
    int stride = gridDim.x * blockDim.x;
    for (int e = blockIdx.x * blockDim.x + threadIdx.x; e < E; e += stride) {
        int d = dst[e];
        int p = offsets[d] + atomicAdd(&cursors[d], 1);
        s_src[p] = src[e];
        s_dst[p] = d;
        s_eid[p] = e;
    }
}

// self-loop edge feature projections: eemean[layer] = (mean ea) @ We_layer
__global__ void eemean_kernel(const float* __restrict__ accum,
                              const float* __restrict__ We0, const float* __restrict__ We1,
                              float* __restrict__ eemean, float invE)
{
    int tid = threadIdx.x;          // 512 threads
    int layer = tid >> 8, c = tid & 255;
    const float* W = layer ? We1 : We0;
    float s = 0.f;
#pragma unroll
    for (int j = 0; j < 32; ++j) s += accum[j] * invE * W[j * 256 + c];
    eemean[layer * 256 + c] = s;
}

// ---------------------------------------------------------------------------
// weight transpose + bf16 convert: out[n][k] = bf16(in[k][n]); in is [K][N]
__global__ __launch_bounds__(256) void transpose_bf16_kernel(const float* __restrict__ in,
                                                             ushortT* __restrict__ out,
                                                             int K, int N)
{
    __shared__ float tile[32][33];
    int bx = blockIdx.x * 32;     // N dim
    int by = blockIdx.y * 32;     // K dim
    int tx = threadIdx.x & 31, ty = threadIdx.x >> 5;
#pragma unroll
    for (int r = 0; r < 32; r += 8) {
        int k = by + ty + r, n = bx + tx;
        if (k < K && n < N) tile[ty + r][tx] = in[(size_t)k * N + n];
    }
    __syncthreads();
#pragma unroll
    for (int r = 0; r < 32; r += 8) {
        int n = bx + ty + r, k = by + tx;
        if (n < N && k < K) out[(size_t)n * K + k] = f2bf(tile[tx][ty + r]);
    }
}

// fused bias [512] = bl | br
__global__ void fuse_bias_kernel(const float* __restrict__ bl, const float* __restrict__ br,
                                 float* __restrict__ out)
{
    int i = threadIdx.x;
    out[i] = (i < 256) ? bl[i] : br[i - 256];
}

// ---------------------------------------------------------------------------
// MFMA bf16 GEMM: C[row,col] = act(A[row,:K] @ Bt[col,:K]^T + bias[col])
// A fp32 [>=Mvalid][K] (staged->bf16), Bt bf16 [Nn][K] (pre-transposed weights).
// 128x128 tile, BK=32, 256 threads = 4 waves (2x2), 16 mfma_16x16x32 per wave/step.
__global__ __launch_bounds__(256) void mfma_gemm_kernel(
    const float* __restrict__ A, const ushortT* __restrict__ Bt,
    const float* __restrict__ bias, float* __restrict__ Cf,
    ushortT* __restrict__ Cb, int K, int Nn, int act)
{
    __shared__ __align__(16) ushortT As[128 * 32];
    __shared__ __align__(16) ushortT Bs[128 * 32];
    int tid = threadIdx.x;
    int brow = blockIdx.x * 128;
    int bcol = blockIdx.y * 128;
    int lane = tid & 63, w = tid >> 6;
    int wr = w >> 1, wc = w & 1;
    int fr = lane & 15, fq = lane >> 4;

    f32x4 acc[4][4];
#pragma unroll
    for (int i = 0; i < 4; ++i)
#pragma unroll
        for (int j = 0; j < 4; ++j)
            acc[i][j] = (f32x4){0.f, 0.f, 0.f, 0.f};

    int r0 = tid >> 2, g0 = tid & 3;
    int r1 = r0 + 64;
    int arow0 = brow + r0, arow1 = brow + r1;
    bool av0 = arow0 < N_NODES, av1 = arow1 < N_NODES;
    const float* Ap0 = A + (size_t)arow0 * K + g0 * 8;
    const float* Ap1 = A + (size_t)arow1 * K + g0 * 8;
    const ushortT* Bp0 = Bt + (size_t)(bcol + r0) * K + g0 * 8;
    const ushortT* Bp1 = Bt + (size_t)(bcol + r1) * K + g0 * 8;
    uint4* asw0 = (uint4*)&As[(size_t)tid * 8];
    uint4* asw1 = (uint4*)&As[(size_t)(tid + 256) * 8];
    uint4* bsw0 = (uint4*)&Bs[(size_t)tid * 8];
    uint4* bsw1 = (uint4*)&Bs[(size_t)(tid + 256) * 8];

    for (int k0 = 0; k0 < K; k0 += 32) {
        float4 z = make_float4(0.f, 0.f, 0.f, 0.f);
        float4 fa0 = z, fa1 = z, fc0 = z, fc1 = z;
        if (av0) { fa0 = *(const float4*)(Ap0 + k0); fc0 = *(const float4*)(Ap0 + k0 + 4); }
        if (av1) { fa1 = *(const float4*)(Ap1 + k0); fc1 = *(const float4*)(Ap1 + k0 + 4); }
        uint4 ub0 = *(const uint4*)(Bp0 + k0);
        uint4 ub1 = *(const uint4*)(Bp1 + k0);
        uint4 ua0, ua1;
        ua0.x = pack2(fa0.x, fa0.y); ua0.y = pack2(fa0.z, fa0.w);
        ua0.z = pack2(fc0.x, fc0.y); ua0.w = pack2(fc0.z, fc0.w);
        ua1.x = pack2(fa1.x, fa1.y); ua1.y = pack2(fa1.z, fa1.w);
        ua1.z = pack2(fc1.x, fc1.y); ua1.w = pack2(fc1.z, fc1.w);
        __syncthreads();
        *asw0 = ua0; *asw1 = ua1;
        *bsw0 = ub0; *bsw1 = ub1;
        __syncthreads();

        bf16x8 af[4], bfv[4];
#pragma unroll
        for (int mi = 0; mi < 4; ++mi)
            af[mi] = *(bf16x8*)&As[(size_t)(wr * 64 + mi * 16 + fr) * 32 + fq * 8];
#pragma unroll
        for (int ni = 0; ni < 4; ++ni)
            bfv[ni] = *(bf16x8*)&Bs[(size_t)(wc * 64 + ni * 16 + fr) * 32 + fq * 8];
#pragma unroll
        for (int mi = 0; mi < 4; ++mi)
#pragma unroll
            for (int ni = 0; ni < 4; ++ni)
                acc[mi][ni] = __builtin_amdgcn_mfma_f32_16x16x32_bf16(
                    af[mi], bfv[ni], acc[mi][ni], 0, 0, 0);
    }

#pragma unroll
    for (int ni = 0; ni < 4; ++ni) {
        int col = bcol + wc * 64 + ni * 16 + fr;
        float bv = bias[col];
#pragma unroll
        for (int mi = 0; mi < 4; ++mi) {
#pragma unroll
            for (int r = 0; r < 4; ++r) {
                int row = brow + wr * 64 + mi * 16 + fq * 4 + r;
                if (row < N_NODES) {
                    float t = acc[mi][ni][r] + bv;
                    if (act == 1) t = t > 0.f ? t : 0.f;
                    if (Cf) Cf[(size_t)row * Nn + col] = t;
                    if (Cb) Cb[(size_t)row * Nn + col] = f2bf(t);
                }
            }
        }
    }
}

// ---------------------------------------------------------------------------
// MFMA edge logits, channel-permuted. Per 64-edge block, 4 waves x 16 edges.
// Wet staged so that MFMA tile mi, C-row j=fq*4+r holds actual channel
// ch = fq*64 + mi*4 + r  -> each lane's 64 channels are the contiguous block
// [fq*64, fq*64+64) = exactly head fq. Epilogue: 16B gathers, no shuffles.
__global__ __launch_bounds__(256) void edge_logits_kernel(
    const float* __restrict__ ea, const int* __restrict__ s_eid,
    const int* __restrict__ s_src, const int* __restrict__ s_dst,
    const ushortT* __restrict__ Wet, const float* __restrict__ att,
    const ushortT* __restrict__ xlr, float* __restrict__ logits)
{
    __shared__ __align__(16) ushortT Wet_lds[256 * 40];
    __shared__ float att_lds[256];
    __shared__ int sidx[64], didx[64], eidv[64];
    int tid = threadIdx.x;
    int brow = blockIdx.x * 64;

    // stage Wet permuted: staged row sr (tile mi = sr>>4, j = sr&15) holds
    // actual channel ch = (j>>2)*64 + mi*4 + (j&3); row stride 40 bf16.
#pragma unroll
    for (int t = 0; t < 4; ++t) {
        int f = tid + t * 256;
        int sr = f >> 2, q = f & 3;
        int mi = sr >> 4, j = sr & 15;
        int ch = ((j >> 2) << 6) + mi * 4 + (j & 3);
        *(uint4*)&Wet_lds[sr * 40 + q * 8] = *(const uint4*)(Wet + (size_t)ch * 32 + q * 8);
    }
    att_lds[tid] = att[tid];
    if (tid < 64) {
        sidx[tid] = s_src[brow + tid];
        didx[tid] = s_dst[brow + tid];
        eidv[tid] = s_eid[brow + tid];
    }
    __syncthreads();

    int lane = tid & 63, w = tid >> 6;
    int fr = lane & 15, fq = lane >> 4;
    int e_lane = w * 16 + fr;

    // b-frag: this lane's edge ea row, floats fq*8..fq*8+7 -> bf16x8
    int eid = eidv[e_lane];
    const float* earow = ea + (size_t)eid * 32 + fq * 8;
    float4 f0 = ((const float4*)earow)[0];
    float4 f1 = ((const float4*)earow)[1];
    union { unsigned u[4]; bf16x8 v; } ub;
    ub.u[0] = pack2(f0.x, f0.y);
    ub.u[1] = pack2(f0.z, f0.w);
    ub.u[2] = pack2(f1.x, f1.y);
    ub.u[3] = pack2(f1.z, f1.w);
    bf16x8 bfrag = ub.v;

    f32x4 acc[16];
#pragma unroll
    for (int mi = 0; mi < 16; ++mi) {
        bf16x8 afrag = *(bf16x8*)&Wet_lds[(mi * 16 + fr) * 40 + fq * 8];
        acc[mi] = __builtin_amdgcn_mfma_f32_16x16x32_bf16(
            afrag, bfrag, (f32x4){0.f, 0.f, 0.f, 0.f}, 0, 0, 0);
    }

    // epilogue: lane owns channels [fq*64, fq*64+64) of its edge = head fq
    int sn = sidx[e_lane], dn = didx[e_lane];
    const ushortT* lxp = xlr + (size_t)sn * 512 + fq * 64;
    const ushortT* rxp = xlr + (size_t)dn * 512 + 256 + fq * 64;
    const float* atp = &att_lds[fq * 64];
    float lgsum = 0.f;
#pragma unroll
    for (int m2 = 0; m2 < 8; ++m2) {
        uint4 lu = *(const uint4*)(lxp + m2 * 8);
        uint4 ru = *(const uint4*)(rxp + m2 * 8);
        float lf[8], rf[8];
        unpack8(lu, lf);
        unpack8(ru, rf);
        float4 a0 = *(const float4*)(atp + m2 * 8);
        float4 a1 = *(const float4*)(atp + m2 * 8 + 4);
        f32x4 e0 = acc[2 * m2];
        f32x4 e1 = acc[2 * m2 + 1];
        float t0 = e0[0] + lf[0] + rf[0]; t0 = t0 > 0.f ? t0 : 0.2f * t0;
        float t1 = e0[1] + lf[1] + rf[1]; t1 = t1 > 0.f ? t1 : 0.2f * t1;
        float t2 = e0[2] + lf[2] + rf[2]; t2 = t2 > 0.f ? t2 : 0.2f * t2;
        float t3 = e0[3] + lf[3] + rf[3]; t3 = t3 > 0.f ? t3 : 0.2f * t3;
        float t4 = e1[0] + lf[4] + rf[4]; t4 = t4 > 0.f ? t4 : 0.2f * t4;
        float t5 = e1[1] + lf[5] + rf[5]; t5 = t5 > 0.f ? t5 : 0.2f * t5;
        float t6 = e1[2] + lf[6] + rf[6]; t6 = t6 > 0.f ? t6 : 0.2f * t6;
        float t7 = e1[3] + lf[7] + rf[7]; t7 = t7 > 0.f ? t7 : 0.2f * t7;
        lgsum += t0 * a0.x + t1 * a0.y + t2 * a0.z + t3 * a0.w
               + t4 * a1.x + t5 * a1.y + t6 * a1.z + t7 * a1.w;
    }
    logits[(size_t)(brow + e_lane) * 4 + fq] = lgsum;
}

// ---------------------------------------------------------------------------
// Pass 1 of attention: one wave per dst node. Computes self-loop logit
// (channel-parallel), streams edge logits (coalesced: 64 consecutive floats
// per iter), reduces max/denominator online, rewrites logits as alpha in
// place, stores self_alpha[node*4+h].
__global__ __launch_bounds__(256) void alpha_kernel(
    const int* __restrict__ offsets, float* __restrict__ logits,
    const float* __restrict__ att, const float* __restrict__ eemean,
    const ushortT* __restrict__ xlr, float* __restrict__ self_alpha)
{
    int lane = threadIdx.x & 63;
    int d = blockIdx.x * 4 + (threadIdx.x >> 6);
    size_t xbase = (size_t)d * 512 + lane * 4;

    // self logit: channel-parallel over 64 lanes x 4 ch
    ushort4 xlu = *(const ushort4*)(xlr + xbase);
    ushort4 xru = *(const ushort4*)(xlr + xbase + 256);
    float4 eem = *(const float4*)(eemean + lane * 4);
    float4 at4 = *(const float4*)(att + lane * 4);
    float t0 = bf2f(xlu.x) + bf2f(xru.x) + eem.x; t0 = t0 > 0.f ? t0 : 0.2f * t0;
    float t1 = bf2f(xlu.y) + bf2f(xru.y) + eem.y; t1 = t1 > 0.f ? t1 : 0.2f * t1;
    float t2 = bf2f(xlu.z) + bf2f(xru.z) + eem.z; t2 = t2 > 0.f ? t2 : 0.2f * t2;
    float t3 = bf2f(xlu.w) + bf2f(xru.w) + eem.w; t3 = t3 > 0.f ? t3 : 0.2f * t3;
    float lgs = t0 * at4.x + t1 * at4.y + t2 * at4.z + t3 * at4.w;
    lgs += __shfl_xor(lgs, 1);
    lgs += __shfl_xor(lgs, 2);
    lgs += __shfl_xor(lgs, 4);
    lgs += __shfl_xor(lgs, 8);                 // 16-group holds self logit[head=lane>>4]
    float lgs_me = __shfl(lgs, (lane & 3) << 4);  // remap: this lane's head = lane&3

    int beg = offsets[d], end = offsets[d + 1];
    int slot = lane >> 2, hd = lane & 3;

    float m = -1e30f, s = 0.f;
    for (int i = beg + slot; i < end; i += 16) {
        float lg = logits[(size_t)i * 4 + hd];
        float nm = fmaxf(m, lg);
        s = s * __expf(m - nm) + __expf(lg - nm);
        m = nm;
    }
    // merge across the 16 edge-slots (keep head grouping: strides 4..32)
#pragma unroll
    for (int o = 4; o < 64; o <<= 1) {
        float m2 = __shfl_xor(m, o);
        float s2 = __shfl_xor(s, o);
        float nm = fmaxf(m, m2);
        s = s * __expf(m - nm) + s2 * __expf(m2 - nm);
        m = nm;
    }
    // merge self-loop
    {
        float nm = fmaxf(m, lgs_me);
        s = s * __expf(m - nm) + __expf(lgs_me - nm);
        m = nm;
    }
    float inv = 1.f / s;
    if (lane < 4) self_alpha[(size_t)d * 4 + lane] = __expf(lgs_me - m) * inv;

    // rewrite logits -> alpha (coalesced, L2-hot)
    for (int i = beg + slot; i < end; i += 16) {
        size_t ix = (size_t)i * 4 + hd;
        logits[ix] = __expf(logits[ix] - m) * inv;
    }
}

// ---------------------------------------------------------------------------
// Pass 2: one wave per dst node. Pure weighted gather-accumulate (no serial
// chain): acc += alpha[e][head] * xl[src]; + self term; +bias, elu, h += ;
// fused graph-norm stats (one atomic pair per block).
__global__ __launch_bounds__(256) void accum_kernel(
    const int* __restrict__ s_src, const int* __restrict__ offsets,
    const float* __restrict__ alpha, const float* __restrict__ self_alpha,
    const float* __restrict__ bias, const ushortT* __restrict__ xlr,
    float* __restrict__ h, float* __restrict__ stats)
{
    int lane = threadIdx.x & 63;
    int wv = threadIdx.x >> 6;
    int d = blockIdx.x * 4 + wv;
    size_t xbase = (size_t)d * 512 + lane * 4;
    size_t hbase = (size_t)d * 256 + lane * 4;
    int head = lane >> 4;

    ushort4 xlu = *(const ushort4*)(xlr + xbase);
    float sa = self_alpha[(size_t)d * 4 + head];
    float acc0 = sa * bf2f(xlu.x);
    float acc1 = sa * bf2f(xlu.y);
    float acc2 = sa * bf2f(xlu.z);
    float acc3 = sa * bf2f(xlu.w);

    int beg = offsets[d], end = offsets[d + 1];

    int idx1 = 0;
    ushort4 x_cur = make_ushort4(0, 0, 0, 0);
    float a_cur = 0.f;
    if (beg < end) {
        int idx0 = s_src[beg];
        x_cur = *(const ushort4*)(xlr + (size_t)idx0 * 512 + lane * 4);
        a_cur = alpha[(size_t)beg * 4 + head];
        if (beg + 1 < end) idx1 = s_src[beg + 1];
    }
    for (int pos = beg; pos < end; ++pos) {
        ushort4 xv = x_cur;
        float av = a_cur;
        int np = pos + 1;
        if (np < end) {
            x_cur = *(const ushort4*)(xlr + (size_t)idx1 * 512 + lane * 4);
            a_cur = alpha[(size_t)np * 4 + head];
        }
        if (pos + 2 < end) idx1 = s_src[pos + 2];
        acc0 += av * bf2f(xv.x);
        acc1 += av * bf2f(xv.y);
        acc2 += av * bf2f(xv.z);
        acc3 += av * bf2f(xv.w);
    }

    float4 b4 = *(const float4*)&bias[lane * 4];
    float4 hv = *(const float4*)(h + hbase);
    float o0 = acc0 + b4.x; o0 = o0 > 0.f ? o0 : __expf(o0) - 1.f;
    float o1 = acc1 + b4.y; o1 = o1 > 0.f ? o1 : __expf(o1) - 1.f;
    float o2 = acc2 + b4.z; o2 = o2 > 0.f ? o2 : __expf(o2) - 1.f;
    float o3 = acc3 + b4.w; o3 = o3 > 0.f ? o3 : __expf(o3) - 1.f;
    float y0 = hv.x + o0, y1 = hv.y + o1, y2 = hv.z + o2, y3 = hv.w + o3;
    *(float4*)(h + hbase) = make_float4(y0, y1, y2, y3);

    // fused graph-norm stats
    float ls = y0 + y1 + y2 + y3;
    float lq = y0 * y0 + y1 * y1 + y2 * y2 + y3 * y3;
#pragma unroll
    for (int o = 1; o < 64; o <<= 1) {
        ls += __shfl_xor(ls, o);
        lq += __shfl_xor(lq, o);
    }
    __shared__ float red[8];
    if (lane == 0) { red[wv * 2] = ls; red[wv * 2 + 1] = lq; }
    __syncthreads();
    if (threadIdx.x == 0) {
        atomicAdd(&stats[0], red[0] + red[2] + red[4] + red[6]);
        atomicAdd(&stats[1], red[1] + red[3] + red[5] + red[7]);
    }
}

// graph-norm scalars
__global__ void norm_finalize_kernel(float* __restrict__ stats)
{
    float invM = 1.f / ((float)N_NODES * 256.f);
    float mu = stats[0] * invM;
    float var = stats[1] * invM - mu * mu;
    stats[2] = mu;
    stats[3] = rsqrtf(var + EPSN);
}

// h = (h - mu) * scale * g[k] + beta[k], in place
__global__ void normalize_kernel(float* __restrict__ h, const float* __restrict__ g,
                                 const float* __restrict__ beta, const float* __restrict__ stats)
{
    float mu = stats[2], sc = stats[3];
    int stride = gridDim.x * blockDim.x;
    int total = N_NODES * 64;      // float4 count
    for (int i = blockIdx.x * blockDim.x + threadIdx.x; i < total; i += stride) {
        float4 v = ((float4*)h)[i];
        int k = (i & 63) * 4;
        float4 gv = *(const float4*)&g[k];
        float4 bv = *(const float4*)&beta[k];
        v.x = (v.x - mu) * sc * gv.x + bv.x;
        v.y = (v.y - mu) * sc * gv.y + bv.y;
        v.z = (v.z - mu) * sc * gv.z + bv.z;
        v.w = (v.w - mu) * sc * gv.w + bv.w;
        ((float4*)h)[i] = v;
    }
}

// ---------------------------------------------------------------------------
extern "C" void kernel_launch(void* const* d_in, const int* in_sizes, int n_in,
                              void* d_out, int out_size, void* d_ws, size_t ws_size,
                              hipStream_t stream)
{
    (void)in_sizes; (void)n_in; (void)out_size; (void)ws_size;
    const float* x     = (const float*)d_in[0];
    const int*   eidx  = (const int*)d_in[1];
    const float* ea    = (const float*)d_in[2];
    const float* W_in  = (const float*)d_in[3];
    const float* b_in  = (const float*)d_in[4];
    const float* W_out = (const float*)d_in[5];
    const float* b_out = (const float*)d_in[6];
    const float* Wl[2]  = {(const float*)d_in[7],  (const float*)d_in[16]};
    const float* bl[2]  = {(const float*)d_in[8],  (const float*)d_in[17]};
    const float* Wr[2]  = {(const float*)d_in[9],  (const float*)d_in[18]};
    const float* br[2]  = {(const float*)d_in[10], (const float*)d_in[19]};
    const float* We[2]  = {(const float*)d_in[11], (const float*)d_in[20]};
    const float* att[2] = {(const float*)d_in[12], (const float*)d_in[21]};
    const float* bias[2]= {(const float*)d_in[13], (const float*)d_in[22]};
    const float* g[2]   = {(const float*)d_in[14], (const float*)d_in[23]};
    const float* beta[2]= {(const float*)d_in[15], (const float*)d_in[24]};

    // workspace layout (~128 MB)
    char* p = (char*)d_ws;
    auto take = [&](size_t bytes) -> char* {
        char* r = p;
        p += (bytes + 255) & ~(size_t)255;
        return r;
    };
    int*   counts  = (int*)take((size_t)N_NODES * 4);
    int*   cursors = (int*)take((size_t)N_NODES * 4);
    float* ea_acc  = (float*)take(32 * 4);
    float* stats   = (float*)take(8 * 4);
    size_t zero_bytes = (size_t)(p - (char*)d_ws);
    int*   offsets = (int*)take((size_t)(N_NODES + 1) * 4);
    int*   s_src   = (int*)take((size_t)E_EDGES * 4);
    int*   s_dst   = (int*)take((size_t)E_EDGES * 4);
    int*   s_eid   = (int*)take((size_t)E_EDGES * 4);
    float* eemean  = (float*)take(512 * 4);
    ushortT* WtIn  = (ushortT*)take((size_t)256 * 384 * 2);
    ushortT* WtLR0 = (ushortT*)take((size_t)512 * 256 * 2);
    ushortT* WtLR1 = (ushortT*)take((size_t)512 * 256 * 2);
    ushortT* WtOut = (ushortT*)take((size_t)256 * 256 * 2);
    ushortT* Wet0  = (ushortT*)take((size_t)256 * 32 * 2);
    ushortT* Wet1  = (ushortT*)take((size_t)256 * 32 * 2);
    float* fb0     = (float*)take(512 * 4);
    float* fb1     = (float*)take(512 * 4);
    ushortT* xlr   = (ushortT*)take((size_t)N_NODES * 512 * 2);
    float* h       = (float*)take((size_t)N_NODES * 256 * 4);
    float* logits  = (float*)take((size_t)E_EDGES * 4 * 4);
    float* selfa   = (float*)take((size_t)N_NODES * 4 * 4);

    const ushortT* WtLR[2] = {WtLR0, WtLR1};
    const ushortT* Wet[2] = {Wet0, Wet1};
    const float* fb[2] = {fb0, fb1};

    const int* srcv = eidx;
    const int* dstv = eidx + E_EDGES;

    hipMemsetAsync(d_ws, 0, zero_bytes, stream);

    ea_accum_kernel<<<512, 256, 0, stream>>>(ea, ea_acc, (long)E_EDGES * 32);
    hist_kernel<<<1024, 256, 0, stream>>>(dstv, counts, E_EDGES);
    scan_kernel<<<1, 1024, 0, stream>>>(counts, offsets, N_NODES);
    scatter_kernel<<<1024, 256, 0, stream>>>(srcv, dstv, offsets, cursors,
                                             s_src, s_dst, s_eid, E_EDGES);
    eemean_kernel<<<1, 512, 0, stream>>>(ea_acc, We[0], We[1], eemean, 1.0f / (float)E_EDGES);

    // weight prep: transpose + bf16
    transpose_bf16_kernel<<<dim3(8, 12), 256, 0, stream>>>(W_in, WtIn, 384, 256);
    transpose_bf16_kernel<<<dim3(8, 8), 256, 0, stream>>>(Wl[0], WtLR0, 256, 256);
    transpose_bf16_kernel<<<dim3(8, 8), 256, 0, stream>>>(Wr[0], WtLR0 + 256 * 256, 256, 256);
    transpose_bf16_kernel<<<dim3(8, 8), 256, 0, stream>>>(Wl[1], WtLR1, 256, 256);
    transpose_bf16_kernel<<<dim3(8, 8), 256, 0, stream>>>(Wr[1], WtLR1 + 256 * 256, 256, 256);
    transpose_bf16_kernel<<<dim3(8, 8), 256, 0, stream>>>(W_out, WtOut, 256, 256);
    transpose_bf16_kernel<<<dim3(8, 1), 256, 0, stream>>>(We[0], Wet0, 32, 256);
    transpose_bf16_kernel<<<dim3(8, 1), 256, 0, stream>>>(We[1], Wet1, 32, 256);
    fuse_bias_kernel<<<1, 512, 0, stream>>>(bl[0], br[0], fb0);
    fuse_bias_kernel<<<1, 512, 0, stream>>>(bl[1], br[1], fb1);

    // h0 = relu(x @ W_in + b_in), fp32
    mfma_gemm_kernel<<<dim3(391, 2), 256, 0, stream>>>(x, WtIn, b_in, h, nullptr, 384, 256, 1);

    for (int l = 0; l < 2; ++l) {
        // fused [xl|xr] = h @ [Wl|Wr] + [bl|br], bf16 packed
        mfma_gemm_kernel<<<dim3(391, 4), 256, 0, stream>>>(h, WtLR[l], fb[l], nullptr, xlr,
                                                           256, 512, 0);
        edge_logits_kernel<<<E_EDGES / 64, 256, 0, stream>>>(ea, s_eid, s_src, s_dst,
                                                             Wet[l], att[l], xlr, logits);
        alpha_kernel<<<N_NODES / 4, 256, 0, stream>>>(offsets, logits, att[l],
                                                      eemean + l * 256, xlr, selfa);
        accum_kernel<<<N_NODES / 4, 256, 0, stream>>>(s_src, offsets, logits, selfa,
                                                      bias[l], xlr, h, stats + l * 4);
        norm_finalize_kernel<<<1, 1, 0, stream>>>(stats + l * 4);
        normalize_kernel<<<2048, 256, 0, stream>>>(h, g[l], beta[l], stats + l * 4);
    }
    // out = h @ W_out + b_out, fp32
    mfma_gemm_kernel<<<dim3(391, 2), 256, 0, stream>>>(h, WtOut, b_out, (float*)d_out, nullptr,
                                                       256, 256, 0);
}

// Round 7
// 1679.580 us; speedup vs baseline: 1.0251x; 1.0251x over previous
//
#include <hip/hip_runtime.h>
#include <hip/hip_bf16.h>

// Problem constants (from reference)
#define N_NODES 50000
#define E_EDGES 800000
#define DIN_K   384
#define DH_N    256
#define EPSN    1e-5f

typedef unsigned short ushortT;
typedef __attribute__((ext_vector_type(4))) float f32x4;
typedef __attribute__((ext_vector_type(8))) short bf16x8;

static __device__ __forceinline__ float bf2f(unsigned short u)
{
    return __uint_as_float(((unsigned)u) << 16);
}
static __device__ __forceinline__ unsigned short f2bf(float f)
{
    unsigned u = __float_as_uint(f);
    unsigned r = (u + 0x7fffu + ((u >> 16) & 1u)) >> 16;   // round-nearest-even
    return (unsigned short)r;
}
static __device__ __forceinline__ unsigned pack2(float a, float b)
{
    return (unsigned)f2bf(a) | ((unsigned)f2bf(b) << 16);
}
static __device__ __forceinline__ void unpack8(uint4 u, float* f)
{
    f[0] = bf2f((ushortT)(u.x & 0xffff)); f[1] = bf2f((ushortT)(u.x >> 16));
    f[2] = bf2f((ushortT)(u.y & 0xffff)); f[3] = bf2f((ushortT)(u.y >> 16));
    f[4] = bf2f((ushortT)(u.z & 0xffff)); f[5] = bf2f((ushortT)(u.z >> 16));
    f[6] = bf2f((ushortT)(u.w & 0xffff)); f[7] = bf2f((ushortT)(u.w >> 16));
}

// ---------------------------------------------------------------------------
// edge_attr column sums (thread always hits column tid%32)
__global__ __launch_bounds__(256) void ea_accum_kernel(const float* __restrict__ ea,
                                                       float* __restrict__ accum, long total)
{
    long stride = (long)gridDim.x * blockDim.x;
    float local = 0.f;
    for (long i = (long)blockIdx.x * blockDim.x + threadIdx.x; i < total; i += stride)
        local += ea[i];
    __shared__ float red[256];
    red[threadIdx.x] = local;
    __syncthreads();
    if (threadIdx.x < 32) {
        float s = 0.f;
#pragma unroll
        for (int r = 0; r < 8; ++r) s += red[r * 32 + threadIdx.x];
        atomicAdd(&accum[threadIdx.x], s);
    }
}

// histogram of dst
__global__ void hist_kernel(const int* __restrict__ dst, int* __restrict__ counts, int E)
{
    int stride = gridDim.x * blockDim.x;
    for (int e = blockIdx.x * blockDim.x + threadIdx.x; e < E; e += stride)
        atomicAdd(&counts[dst[e]], 1);
}

// exclusive scan of counts -> offsets[N+1], single block
__global__ __launch_bounds__(1024) void scan_kernel(const int* __restrict__ counts,
                                                    int* __restrict__ offsets, int Nn)
{
    __shared__ int sdata[1024];
    __shared__ int run_s;
    int tid = threadIdx.x;
    if (tid == 0) run_s = 0;
    __syncthreads();
    for (int base2 = 0; base2 < Nn; base2 += 1024) {
        int i = base2 + tid;
        int v = (i < Nn) ? counts[i] : 0;
        sdata[tid] = v;
        __syncthreads();
        for (int off = 1; off < 1024; off <<= 1) {
            int t = (tid >= off) ? sdata[tid - off] : 0;
            __syncthreads();
            sdata[tid] += t;
            __syncthreads();
        }
        int run = run_s;
        if (i < Nn) offsets[i] = run + sdata[tid] - v;   // exclusive
        int tot = sdata[1023];
        __syncthreads();
        if (tid == 0) run_s = run + tot;
        __syncthreads();
    }
    if (tid == 0) offsets[Nn] = run_s;
}

// scatter edges into dst-sorted order
__global__ void scatter_kernel(const int* __restrict__ src, const int* __restrict__ dst,
                               const int* __restrict__ offsets, int* __restrict__ cursors,
                               int* __restrict__ s_src, int* __restrict__ s_dst,
                               int* __restrict__ s_eid, int E)
{
    int stride = gridDim.x * blockDim.x;
    for (int e = blockIdx.x * blockDim.x + threadIdx.x; e < E; e += stride) {
        int d = dst[e];
        int p = offsets[d] + atomicAdd(&cursors[d], 1);
        s_src[p] = src[e];
        s_dst[p] = d;
        s_eid[p] = e;
    }
}

// self-loop edge feature projections: eemean[layer] = (mean ea) @ We_layer
__global__ void eemean_kernel(const float* __restrict__ accum,
                              const float* __restrict__ We0, const float* __restrict__ We1,
                              float* __restrict__ eemean, float invE)
{
    int tid = threadIdx.x;          // 512 threads
    int layer = tid >> 8, c = tid & 255;
    const float* W = layer ? We1 : We0;
    float s = 0.f;
#pragma unroll
    for (int j = 0; j < 32; ++j) s += accum[j] * invE * W[j * 256 + c];
    eemean[layer * 256 + c] = s;
}

// ---------------------------------------------------------------------------
// weight transpose + bf16 convert: out[n][k] = bf16(in[k][n]); in is [K][N]
__global__ __launch_bounds__(256) void transpose_bf16_kernel(const float* __restrict__ in,
                                                             ushortT* __restrict__ out,
                                                             int K, int N)
{
    __shared__ float tile[32][33];
    int bx = blockIdx.x * 32;     // N dim
    int by = blockIdx.y * 32;     // K dim
    int tx = threadIdx.x & 31, ty = threadIdx.x >> 5;
#pragma unroll
    for (int r = 0; r < 32; r += 8) {
        int k = by + ty + r, n = bx + tx;
        if (k < K && n < N) tile[ty + r][tx] = in[(size_t)k * N + n];
    }
    __syncthreads();
#pragma unroll
    for (int r = 0; r < 32; r += 8) {
        int n = bx + ty + r, k = by + tx;
        if (n < N && k < K) out[(size_t)n * K + k] = f2bf(tile[tx][ty + r]);
    }
}

// fused bias [512] = bl | br
__global__ void fuse_bias_kernel(const float* __restrict__ bl, const float* __restrict__ br,
                                 float* __restrict__ out)
{
    int i = threadIdx.x;
    out[i] = (i < 256) ? bl[i] : br[i - 256];
}

// ---------------------------------------------------------------------------
// MFMA bf16 GEMM: C[row,col] = act(A[row,:K] @ Bt[col,:K]^T + bias[col])
// A fp32 [>=Mvalid][K] (staged->bf16), Bt bf16 [Nn][K] (pre-transposed weights).
// 128x128 tile, BK=32, 256 threads = 4 waves (2x2), 16 mfma_16x16x32 per wave/step.
__global__ __launch_bounds__(256) void mfma_gemm_kernel(
    const float* __restrict__ A, const ushortT* __restrict__ Bt,
    const float* __restrict__ bias, float* __restrict__ Cf,
    ushortT* __restrict__ Cb, int K, int Nn, int act)
{
    __shared__ __align__(16) ushortT As[128 * 32];
    __shared__ __align__(16) ushortT Bs[128 * 32];
    int tid = threadIdx.x;
    int brow = blockIdx.x * 128;
    int bcol = blockIdx.y * 128;
    int lane = tid & 63, w = tid >> 6;
    int wr = w >> 1, wc = w & 1;
    int fr = lane & 15, fq = lane >> 4;

    f32x4 acc[4][4];
#pragma unroll
    for (int i = 0; i < 4; ++i)
#pragma unroll
        for (int j = 0; j < 4; ++j)
            acc[i][j] = (f32x4){0.f, 0.f, 0.f, 0.f};

    int r0 = tid >> 2, g0 = tid & 3;
    int r1 = r0 + 64;
    int arow0 = brow + r0, arow1 = brow + r1;
    bool av0 = arow0 < N_NODES, av1 = arow1 < N_NODES;
    const float* Ap0 = A + (size_t)arow0 * K + g0 * 8;
    const float* Ap1 = A + (size_t)arow1 * K + g0 * 8;
    const ushortT* Bp0 = Bt + (size_t)(bcol + r0) * K + g0 * 8;
    const ushortT* Bp1 = Bt + (size_t)(bcol + r1) * K + g0 * 8;
    uint4* asw0 = (uint4*)&As[(size_t)tid * 8];
    uint4* asw1 = (uint4*)&As[(size_t)(tid + 256) * 8];
    uint4* bsw0 = (uint4*)&Bs[(size_t)tid * 8];
    uint4* bsw1 = (uint4*)&Bs[(size_t)(tid + 256) * 8];

    for (int k0 = 0; k0 < K; k0 += 32) {
        float4 z = make_float4(0.f, 0.f, 0.f, 0.f);
        float4 fa0 = z, fa1 = z, fc0 = z, fc1 = z;
        if (av0) { fa0 = *(const float4*)(Ap0 + k0); fc0 = *(const float4*)(Ap0 + k0 + 4); }
        if (av1) { fa1 = *(const float4*)(Ap1 + k0); fc1 = *(const float4*)(Ap1 + k0 + 4); }
        uint4 ub0 = *(const uint4*)(Bp0 + k0);
        uint4 ub1 = *(const uint4*)(Bp1 + k0);
        uint4 ua0, ua1;
        ua0.x = pack2(fa0.x, fa0.y); ua0.y = pack2(fa0.z, fa0.w);
        ua0.z = pack2(fc0.x, fc0.y); ua0.w = pack2(fc0.z, fc0.w);
        ua1.x = pack2(fa1.x, fa1.y); ua1.y = pack2(fa1.z, fa1.w);
        ua1.z = pack2(fc1.x, fc1.y); ua1.w = pack2(fc1.z, fc1.w);
        __syncthreads();
        *asw0 = ua0; *asw1 = ua1;
        *bsw0 = ub0; *bsw1 = ub1;
        __syncthreads();

        bf16x8 af[4], bfv[4];
#pragma unroll
        for (int mi = 0; mi < 4; ++mi)
            af[mi] = *(bf16x8*)&As[(size_t)(wr * 64 + mi * 16 + fr) * 32 + fq * 8];
#pragma unroll
        for (int ni = 0; ni < 4; ++ni)
            bfv[ni] = *(bf16x8*)&Bs[(size_t)(wc * 64 + ni * 16 + fr) * 32 + fq * 8];
#pragma unroll
        for (int mi = 0; mi < 4; ++mi)
#pragma unroll
            for (int ni = 0; ni < 4; ++ni)
                acc[mi][ni] = __builtin_amdgcn_mfma_f32_16x16x32_bf16(
                    af[mi], bfv[ni], acc[mi][ni], 0, 0, 0);
    }

#pragma unroll
    for (int ni = 0; ni < 4; ++ni) {
        int col = bcol + wc * 64 + ni * 16 + fr;
        float bv = bias[col];
#pragma unroll
        for (int mi = 0; mi < 4; ++mi) {
#pragma unroll
            for (int r = 0; r < 4; ++r) {
                int row = brow + wr * 64 + mi * 16 + fq * 4 + r;
                if (row < N_NODES) {
                    float t = acc[mi][ni][r] + bv;
                    if (act == 1) t = t > 0.f ? t : 0.f;
                    if (Cf) Cf[(size_t)row * Nn + col] = t;
                    if (Cb) Cb[(size_t)row * Nn + col] = f2bf(t);
                }
            }
        }
    }
}

// ---------------------------------------------------------------------------
// MFMA edge logits, channel-permuted. Per 64-edge block, 4 waves x 16 edges.
// Wet staged so that MFMA tile mi, C-row j=fq*4+r holds actual channel
// ch = fq*64 + mi*4 + r  -> each lane's 64 channels are the contiguous block
// [fq*64, fq*64+64) = exactly head fq. Epilogue: 16B gathers, no shuffles.
__global__ __launch_bounds__(256) void edge_logits_kernel(
    const float* __restrict__ ea, const int* __restrict__ s_eid,
    const int* __restrict__ s_src, const int* __restrict__ s_dst,
    const ushortT* __restrict__ Wet, const float* __restrict__ att,
    const ushortT* __restrict__ xlr, float* __restrict__ logits)
{
    __shared__ __align__(16) ushortT Wet_lds[256 * 40];
    __shared__ float att_lds[256];
    __shared__ int sidx[64], didx[64], eidv[64];
    int tid = threadIdx.x;
    int brow = blockIdx.x * 64;

    // stage Wet permuted: staged row sr (tile mi = sr>>4, j = sr&15) holds
    // actual channel ch = (j>>2)*64 + mi*4 + (j&3); row stride 40 bf16.
#pragma unroll
    for (int t = 0; t < 4; ++t) {
        int f = tid + t * 256;
        int sr = f >> 2, q = f & 3;
        int mi = sr >> 4, j = sr & 15;
        int ch = ((j >> 2) << 6) + mi * 4 + (j & 3);
        *(uint4*)&Wet_lds[sr * 40 + q * 8] = *(const uint4*)(Wet + (size_t)ch * 32 + q * 8);
    }
    att_lds[tid] = att[tid];
    if (tid < 64) {
        sidx[tid] = s_src[brow + tid];
        didx[tid] = s_dst[brow + tid];
        eidv[tid] = s_eid[brow + tid];
    }
    __syncthreads();

    int lane = tid & 63, w = tid >> 6;
    int fr = lane & 15, fq = lane >> 4;
    int e_lane = w * 16 + fr;

    // b-frag: this lane's edge ea row, floats fq*8..fq*8+7 -> bf16x8
    int eid = eidv[e_lane];
    const float* earow = ea + (size_t)eid * 32 + fq * 8;
    float4 f0 = ((const float4*)earow)[0];
    float4 f1 = ((const float4*)earow)[1];
    union { unsigned u[4]; bf16x8 v; } ub;
    ub.u[0] = pack2(f0.x, f0.y);
    ub.u[1] = pack2(f0.z, f0.w);
    ub.u[2] = pack2(f1.x, f1.y);
    ub.u[3] = pack2(f1.z, f1.w);
    bf16x8 bfrag = ub.v;

    f32x4 acc[16];
#pragma unroll
    for (int mi = 0; mi < 16; ++mi) {
        bf16x8 afrag = *(bf16x8*)&Wet_lds[(mi * 16 + fr) * 40 + fq * 8];
        acc[mi] = __builtin_amdgcn_mfma_f32_16x16x32_bf16(
            afrag, bfrag, (f32x4){0.f, 0.f, 0.f, 0.f}, 0, 0, 0);
    }

    // epilogue: lane owns channels [fq*64, fq*64+64) of its edge = head fq
    int sn = sidx[e_lane], dn = didx[e_lane];
    const ushortT* lxp = xlr + (size_t)sn * 512 + fq * 64;
    const ushortT* rxp = xlr + (size_t)dn * 512 + 256 + fq * 64;
    const float* atp = &att_lds[fq * 64];
    float lgsum = 0.f;
#pragma unroll
    for (int m2 = 0; m2 < 8; ++m2) {
        uint4 lu = *(const uint4*)(lxp + m2 * 8);
        uint4 ru = *(const uint4*)(rxp + m2 * 8);
        float lf[8], rf[8];
        unpack8(lu, lf);
        unpack8(ru, rf);
        float4 a0 = *(const float4*)(atp + m2 * 8);
        float4 a1 = *(const float4*)(atp + m2 * 8 + 4);
        f32x4 e0 = acc[2 * m2];
        f32x4 e1 = acc[2 * m2 + 1];
        float t0 = e0[0] + lf[0] + rf[0]; t0 = t0 > 0.f ? t0 : 0.2f * t0;
        float t1 = e0[1] + lf[1] + rf[1]; t1 = t1 > 0.f ? t1 : 0.2f * t1;
        float t2 = e0[2] + lf[2] + rf[2]; t2 = t2 > 0.f ? t2 : 0.2f * t2;
        float t3 = e0[3] + lf[3] + rf[3]; t3 = t3 > 0.f ? t3 : 0.2f * t3;
        float t4 = e1[0] + lf[4] + rf[4]; t4 = t4 > 0.f ? t4 : 0.2f * t4;
        float t5 = e1[1] + lf[5] + rf[5]; t5 = t5 > 0.f ? t5 : 0.2f * t5;
        float t6 = e1[2] + lf[6] + rf[6]; t6 = t6 > 0.f ? t6 : 0.2f * t6;
        float t7 = e1[3] + lf[7] + rf[7]; t7 = t7 > 0.f ? t7 : 0.2f * t7;
        lgsum += t0 * a0.x + t1 * a0.y + t2 * a0.z + t3 * a0.w
               + t4 * a1.x + t5 * a1.y + t6 * a1.z + t7 * a1.w;
    }
    logits[(size_t)(brow + e_lane) * 4 + fq] = lgsum;
}

// ---------------------------------------------------------------------------
// Fused attention: one wave per dst node, chunk-8 software pipeline.
// Pipeline: indices 2 chunks ahead (wave-uniform s_load), xlr rows + logits
// 1 chunk ahead (8 concurrent 512B gathers/wave), chunk-level online softmax.
// Epilogue: +bias, elu, h += hn, fused graph-norm stats.
__global__ __launch_bounds__(256) void edge_attn_kernel(
    const int* __restrict__ s_src, const int* __restrict__ offsets,
    const float* __restrict__ logits,
    const float* __restrict__ att, const float* __restrict__ bias,
    const float* __restrict__ eemean,
    const ushortT* __restrict__ xlr, float* __restrict__ h,
    float* __restrict__ stats)
{
    int lane = threadIdx.x & 63;
    int wv = threadIdx.x >> 6;
    int d = blockIdx.x * 4 + wv;
    size_t xbase = (size_t)d * 512 + lane * 4;
    size_t hbase = (size_t)d * 256 + lane * 4;
    int head = lane >> 4;

    ushort4 xlu = *(const ushort4*)(xlr + xbase);
    ushort4 xru = *(const ushort4*)(xlr + xbase + 256);
    float xs0 = bf2f(xlu.x), xs1 = bf2f(xlu.y), xs2 = bf2f(xlu.z), xs3 = bf2f(xlu.w);
    float xr0 = bf2f(xru.x), xr1 = bf2f(xru.y), xr2 = bf2f(xru.z), xr3 = bf2f(xru.w);
    float4 eem = *(const float4*)(eemean + lane * 4);
    float4 at4 = *(const float4*)(att + lane * 4);

    // self-loop logit (channel-parallel, then head-group reduce)
    float t0 = xs0 + xr0 + eem.x; t0 = t0 > 0.f ? t0 : 0.2f * t0;
    float t1 = xs1 + xr1 + eem.y; t1 = t1 > 0.f ? t1 : 0.2f * t1;
    float t2 = xs2 + xr2 + eem.z; t2 = t2 > 0.f ? t2 : 0.2f * t2;
    float t3 = xs3 + xr3 + eem.w; t3 = t3 > 0.f ? t3 : 0.2f * t3;
    float lgs = t0 * at4.x + t1 * at4.y + t2 * at4.z + t3 * at4.w;
    lgs += __shfl_xor(lgs, 1);
    lgs += __shfl_xor(lgs, 2);
    lgs += __shfl_xor(lgs, 4);
    lgs += __shfl_xor(lgs, 8);   // 16-lane head group holds self logit for head

    int beg = offsets[d], end = offsets[d + 1];

    float m = -1e30f, s = 0.f;
    float acc0 = 0.f, acc1 = 0.f, acc2 = 0.f, acc3 = 0.f;

    int idxC[8];         // indices for the chunk whose data loads next
    ushort4 xD[8];       // data for current compute chunk
    float lgD[8];

    if (beg < end) {
        // prologue: chunk 0 indices
#pragma unroll
        for (int j = 0; j < 8; ++j) {
            int p = beg + j;
            idxC[j] = s_src[p < E_EDGES ? p : E_EDGES - 1];
        }
        // chunk 0 data
#pragma unroll
        for (int j = 0; j < 8; ++j) {
            xD[j] = *(const ushort4*)(xlr + (size_t)idxC[j] * 512 + lane * 4);
            int p = beg + j;
            float lv = logits[(size_t)(p < E_EDGES ? p : E_EDGES - 1) * 4 + head];
            lgD[j] = (p < end) ? lv : -1e30f;
        }
        // chunk 1 indices
#pragma unroll
        for (int j = 0; j < 8; ++j) {
            int p = beg + 8 + j;
            idxC[j] = s_src[p < E_EDGES ? p : E_EDGES - 1];
        }
    }

    for (int base = beg; base < end; base += 8) {
        bool more1 = (base + 8) < end;
        bool more2 = (base + 16) < end;
        int idxN[8];
        ushort4 xN[8];
        float lgN[8];
        if (more2) {
            // indices for chunk +2
#pragma unroll
            for (int j = 0; j < 8; ++j) {
                int p = base + 16 + j;
                idxN[j] = s_src[p < E_EDGES ? p : E_EDGES - 1];
            }
        }
        if (more1) {
            // data for chunk +1 (8 concurrent gathers)
#pragma unroll
            for (int j = 0; j < 8; ++j) {
                xN[j] = *(const ushort4*)(xlr + (size_t)idxC[j] * 512 + lane * 4);
                int p = base + 8 + j;
                float lv = logits[(size_t)(p < E_EDGES ? p : E_EDGES - 1) * 4 + head];
                lgN[j] = (p < end) ? lv : -1e30f;
            }
        }

        // compute current chunk: chunk max tree -> one rescale -> 8 indep exps
        float c01 = fmaxf(lgD[0], lgD[1]);
        float c23 = fmaxf(lgD[2], lgD[3]);
        float c45 = fmaxf(lgD[4], lgD[5]);
        float c67 = fmaxf(lgD[6], lgD[7]);
        float cm = fmaxf(fmaxf(c01, c23), fmaxf(c45, c67));
        float nm = fmaxf(m, cm);
        float sc = __expf(m - nm);
        float e[8];
#pragma unroll
        for (int j = 0; j < 8; ++j) e[j] = __expf(lgD[j] - nm);
        float se = ((e[0] + e[1]) + (e[2] + e[3])) + ((e[4] + e[5]) + (e[6] + e[7]));
        float sx = 0.f, sy = 0.f, sz = 0.f, sw = 0.f;
#pragma unroll
        for (int j = 0; j < 8; ++j) {
            sx += e[j] * bf2f(xD[j].x);
            sy += e[j] * bf2f(xD[j].y);
            sz += e[j] * bf2f(xD[j].z);
            sw += e[j] * bf2f(xD[j].w);
        }
        s = s * sc + se;
        acc0 = acc0 * sc + sx;
        acc1 = acc1 * sc + sy;
        acc2 = acc2 * sc + sz;
        acc3 = acc3 * sc + sw;
        m = nm;

        if (more1) {
#pragma unroll
            for (int j = 0; j < 8; ++j) {
                xD[j] = xN[j];
                lgD[j] = lgN[j];
                idxC[j] = idxN[j];
            }
        }
    }

    // merge self-loop
    {
        float nm = fmaxf(m, lgs);
        float sc = __expf(m - nm);
        float pr = __expf(lgs - nm);
        s = s * sc + pr;
        acc0 = acc0 * sc + pr * xs0;
        acc1 = acc1 * sc + pr * xs1;
        acc2 = acc2 * sc + pr * xs2;
        acc3 = acc3 * sc + pr * xs3;
    }

    float inv = 1.f / s;
    float4 b4 = *(const float4*)&bias[lane * 4];
    float4 hv = *(const float4*)(h + hbase);
    float o0 = acc0 * inv + b4.x; o0 = o0 > 0.f ? o0 : __expf(o0) - 1.f;
    float o1 = acc1 * inv + b4.y; o1 = o1 > 0.f ? o1 : __expf(o1) - 1.f;
    float o2 = acc2 * inv + b4.z; o2 = o2 > 0.f ? o2 : __expf(o2) - 1.f;
    float o3 = acc3 * inv + b4.w; o3 = o3 > 0.f ? o3 : __expf(o3) - 1.f;
    float y0 = hv.x + o0, y1 = hv.y + o1, y2 = hv.z + o2, y3 = hv.w + o3;
    *(float4*)(h + hbase) = make_float4(y0, y1, y2, y3);

    // fused graph-norm stats
    float ls = y0 + y1 + y2 + y3;
    float lq = y0 * y0 + y1 * y1 + y2 * y2 + y3 * y3;
#pragma unroll
    for (int o = 1; o < 64; o <<= 1) {
        ls += __shfl_xor(ls, o);
        lq += __shfl_xor(lq, o);
    }
    __shared__ float red[8];
    if (lane == 0) { red[wv * 2] = ls; red[wv * 2 + 1] = lq; }
    __syncthreads();
    if (threadIdx.x == 0) {
        atomicAdd(&stats[0], red[0] + red[2] + red[4] + red[6]);
        atomicAdd(&stats[1], red[1] + red[3] + red[5] + red[7]);
    }
}

// graph-norm scalars
__global__ void norm_finalize_kernel(float* __restrict__ stats)
{
    float invM = 1.f / ((float)N_NODES * 256.f);
    float mu = stats[0] * invM;
    float var = stats[1] * invM - mu * mu;
    stats[2] = mu;
    stats[3] = rsqrtf(var + EPSN);
}

// h = (h - mu) * scale * g[k] + beta[k], in place
__global__ void normalize_kernel(float* __restrict__ h, const float* __restrict__ g,
                                 const float* __restrict__ beta, const float* __restrict__ stats)
{
    float mu = stats[2], sc = stats[3];
    int stride = gridDim.x * blockDim.x;
    int total = N_NODES * 64;      // float4 count
    for (int i = blockIdx.x * blockDim.x + threadIdx.x; i < total; i += stride) {
        float4 v = ((float4*)h)[i];
        int k = (i & 63) * 4;
        float4 gv = *(const float4*)&g[k];
        float4 bv = *(const float4*)&beta[k];
        v.x = (v.x - mu) * sc * gv.x + bv.x;
        v.y = (v.y - mu) * sc * gv.y + bv.y;
        v.z = (v.z - mu) * sc * gv.z + bv.z;
        v.w = (v.w - mu) * sc * gv.w + bv.w;
        ((float4*)h)[i] = v;
    }
}

// ---------------------------------------------------------------------------
extern "C" void kernel_launch(void* const* d_in, const int* in_sizes, int n_in,
                              void* d_out, int out_size, void* d_ws, size_t ws_size,
                              hipStream_t stream)
{
    (void)in_sizes; (void)n_in; (void)out_size; (void)ws_size;
    const float* x     = (const float*)d_in[0];
    const int*   eidx  = (const int*)d_in[1];
    const float* ea    = (const float*)d_in[2];
    const float* W_in  = (const float*)d_in[3];
    const float* b_in  = (const float*)d_in[4];
    const float* W_out = (const float*)d_in[5];
    const float* b_out = (const float*)d_in[6];
    const float* Wl[2]  = {(const float*)d_in[7],  (const float*)d_in[16]};
    const float* bl[2]  = {(const float*)d_in[8],  (const float*)d_in[17]};
    const float* Wr[2]  = {(const float*)d_in[9],  (const float*)d_in[18]};
    const float* br[2]  = {(const float*)d_in[10], (const float*)d_in[19]};
    const float* We[2]  = {(const float*)d_in[11], (const float*)d_in[20]};
    const float* att[2] = {(const float*)d_in[12], (const float*)d_in[21]};
    const float* bias[2]= {(const float*)d_in[13], (const float*)d_in[22]};
    const float* g[2]   = {(const float*)d_in[14], (const float*)d_in[23]};
    const float* beta[2]= {(const float*)d_in[15], (const float*)d_in[24]};

    // workspace layout (~127 MB)
    char* p = (char*)d_ws;
    auto take = [&](size_t bytes) -> char* {
        char* r = p;
        p += (bytes + 255) & ~(size_t)255;
        return r;
    };
    int*   counts  = (int*)take((size_t)N_NODES * 4);
    int*   cursors = (int*)take((size_t)N_NODES * 4);
    float* ea_acc  = (float*)take(32 * 4);
    float* stats   = (float*)take(8 * 4);
    size_t zero_bytes = (size_t)(p - (char*)d_ws);
    int*   offsets = (int*)take((size_t)(N_NODES + 1) * 4);
    int*   s_src   = (int*)take((size_t)E_EDGES * 4);
    int*   s_dst   = (int*)take((size_t)E_EDGES * 4);
    int*   s_eid   = (int*)take((size_t)E_EDGES * 4);
    float* eemean  = (float*)take(512 * 4);
    ushortT* WtIn  = (ushortT*)take((size_t)256 * 384 * 2);
    ushortT* WtLR0 = (ushortT*)take((size_t)512 * 256 * 2);
    ushortT* WtLR1 = (ushortT*)take((size_t)512 * 256 * 2);
    ushortT* WtOut = (ushortT*)take((size_t)256 * 256 * 2);
    ushortT* Wet0  = (ushortT*)take((size_t)256 * 32 * 2);
    ushortT* Wet1  = (ushortT*)take((size_t)256 * 32 * 2);
    float* fb0     = (float*)take(512 * 4);
    float* fb1     = (float*)take(512 * 4);
    ushortT* xlr   = (ushortT*)take((size_t)N_NODES * 512 * 2);
    float* h       = (float*)take((size_t)N_NODES * 256 * 4);
    float* logits  = (float*)take((size_t)E_EDGES * 4 * 4);

    const ushortT* WtLR[2] = {WtLR0, WtLR1};
    const ushortT* Wet[2] = {Wet0, Wet1};
    const float* fb[2] = {fb0, fb1};

    const int* srcv = eidx;
    const int* dstv = eidx + E_EDGES;

    hipMemsetAsync(d_ws, 0, zero_bytes, stream);

    ea_accum_kernel<<<512, 256, 0, stream>>>(ea, ea_acc, (long)E_EDGES * 32);
    hist_kernel<<<1024, 256, 0, stream>>>(dstv, counts, E_EDGES);
    scan_kernel<<<1, 1024, 0, stream>>>(counts, offsets, N_NODES);
    scatter_kernel<<<1024, 256, 0, stream>>>(srcv, dstv, offsets, cursors,
                                             s_src, s_dst, s_eid, E_EDGES);
    eemean_kernel<<<1, 512, 0, stream>>>(ea_acc, We[0], We[1], eemean, 1.0f / (float)E_EDGES);

    // weight prep: transpose + bf16
    transpose_bf16_kernel<<<dim3(8, 12), 256, 0, stream>>>(W_in, WtIn, 384, 256);
    transpose_bf16_kernel<<<dim3(8, 8), 256, 0, stream>>>(Wl[0], WtLR0, 256, 256);
    transpose_bf16_kernel<<<dim3(8, 8), 256, 0, stream>>>(Wr[0], WtLR0 + 256 * 256, 256, 256);
    transpose_bf16_kernel<<<dim3(8, 8), 256, 0, stream>>>(Wl[1], WtLR1, 256, 256);
    transpose_bf16_kernel<<<dim3(8, 8), 256, 0, stream>>>(Wr[1], WtLR1 + 256 * 256, 256, 256);
    transpose_bf16_kernel<<<dim3(8, 8), 256, 0, stream>>>(W_out, WtOut, 256, 256);
    transpose_bf16_kernel<<<dim3(8, 1), 256, 0, stream>>>(We[0], Wet0, 32, 256);
    transpose_bf16_kernel<<<dim3(8, 1), 256, 0, stream>>>(We[1], Wet1, 32, 256);
    fuse_bias_kernel<<<1, 512, 0, stream>>>(bl[0], br[0], fb0);
    fuse_bias_kernel<<<1, 512, 0, stream>>>(bl[1], br[1], fb1);

    // h0 = relu(x @ W_in + b_in), fp32
    mfma_gemm_kernel<<<dim3(391, 2), 256, 0, stream>>>(x, WtIn, b_in, h, nullptr, 384, 256, 1);

    for (int l = 0; l < 2; ++l) {
        // fused [xl|xr] = h @ [Wl|Wr] + [bl|br], bf16 packed
        mfma_gemm_kernel<<<dim3(391, 4), 256, 0, stream>>>(h, WtLR[l], fb[l], nullptr, xlr,
                                                           256, 512, 0);
        edge_logits_kernel<<<E_EDGES / 64, 256, 0, stream>>>(ea, s_eid, s_src, s_dst,
                                                             Wet[l], att[l], xlr, logits);
        edge_attn_kernel<<<N_NODES / 4, 256, 0, stream>>>(s_src, offsets, logits,
                                                          att[l], bias[l], eemean + l * 256,
                                                          xlr, h, stats + l * 4);
        norm_finalize_kernel<<<1, 1, 0, stream>>>(stats + l * 4);
        normalize_kernel<<<2048, 256, 0, stream>>>(h, g[l], beta[l], stats + l * 4);
    }
    // out = h @ W_out + b_out, fp32
    mfma_gemm_kernel<<<dim3(391, 2), 256, 0, stream>>>(h, WtOut, b_out, (float*)d_out, nullptr,
                                                       256, 256, 0);
}

// Round 8
// 1623.288 us; speedup vs baseline: 1.0606x; 1.0347x over previous
//
#include <hip/hip_runtime.h>
#include <hip/hip_bf16.h>

// Problem constants (from reference)
#define N_NODES 50000
#define E_EDGES 800000
#define DIN_K   384
#define DH_N    256
#define EPSN    1e-5f

typedef unsigned short ushortT;
typedef __attribute__((ext_vector_type(4))) float f32x4;
typedef __attribute__((ext_vector_type(8))) short bf16x8;

static __device__ __forceinline__ float bf2f(unsigned short u)
{
    return __uint_as_float(((unsigned)u) << 16);
}
static __device__ __forceinline__ unsigned short f2bf(float f)
{
    unsigned u = __float_as_uint(f);
    unsigned r = (u + 0x7fffu + ((u >> 16) & 1u)) >> 16;   // round-nearest-even
    return (unsigned short)r;
}
static __device__ __forceinline__ unsigned pack2(float a, float b)
{
    return (unsigned)f2bf(a) | ((unsigned)f2bf(b) << 16);
}
static __device__ __forceinline__ void unpack8(uint4 u, float* f)
{
    f[0] = bf2f((ushortT)(u.x & 0xffff)); f[1] = bf2f((ushortT)(u.x >> 16));
    f[2] = bf2f((ushortT)(u.y & 0xffff)); f[3] = bf2f((ushortT)(u.y >> 16));
    f[4] = bf2f((ushortT)(u.z & 0xffff)); f[5] = bf2f((ushortT)(u.z >> 16));
    f[6] = bf2f((ushortT)(u.w & 0xffff)); f[7] = bf2f((ushortT)(u.w >> 16));
}

// ---------------------------------------------------------------------------
// combined prep: edge_attr column sums + dst histogram (one launch)
__global__ __launch_bounds__(256) void prep_kernel(const float* __restrict__ ea,
                                                   float* __restrict__ accum,
                                                   const int* __restrict__ dst,
                                                   int* __restrict__ counts)
{
    int gstride = gridDim.x * blockDim.x;
    long total = (long)E_EDGES * 32;
    float local = 0.f;
    for (long i = (long)blockIdx.x * blockDim.x + threadIdx.x; i < total; i += gstride)
        local += ea[i];
    __shared__ float red[256];
    red[threadIdx.x] = local;
    __syncthreads();
    if (threadIdx.x < 32) {
        float s = 0.f;
#pragma unroll
        for (int r = 0; r < 8; ++r) s += red[r * 32 + threadIdx.x];
        atomicAdd(&accum[threadIdx.x], s);
    }
    for (int e = blockIdx.x * blockDim.x + threadIdx.x; e < E_EDGES; e += gstride)
        atomicAdd(&counts[dst[e]], 1);
}

// exclusive scan of counts -> offsets[N+1] (wave-shuffle scan, 2 barriers/chunk)
// + eemean tail: eemean[layer] = (mean ea) @ We_layer
__global__ __launch_bounds__(1024) void scan_eemean_kernel(
    const int* __restrict__ counts, int* __restrict__ offsets,
    const float* __restrict__ ea_acc, const float* __restrict__ We0,
    const float* __restrict__ We1, float* __restrict__ eemean, float invE)
{
    __shared__ int wtot[16];
    int tid = threadIdx.x, lane = tid & 63, wv = tid >> 6;
    int run = 0;
    for (int base = 0; base < N_NODES; base += 1024) {
        int i = base + tid;
        int v = (i < N_NODES) ? counts[i] : 0;
        int sc = v;
#pragma unroll
        for (int off = 1; off < 64; off <<= 1) {
            int t = __shfl_up(sc, off);
            if (lane >= off) sc += t;
        }
        if (lane == 63) wtot[wv] = sc;
        __syncthreads();
        int wpre = 0, tot = 0;
#pragma unroll
        for (int k = 0; k < 16; ++k) {
            int t = wtot[k];
            if (k < wv) wpre += t;
            tot += t;
        }
        if (i < N_NODES) offsets[i] = run + wpre + sc - v;   // exclusive
        run += tot;
        __syncthreads();
    }
    if (tid == 0) offsets[N_NODES] = run;
    // eemean tail
    if (tid < 512) {
        int layer = tid >> 8, c = tid & 255;
        const float* W = layer ? We1 : We0;
        float s = 0.f;
#pragma unroll
        for (int j = 0; j < 32; ++j) s += ea_acc[j] * invE * W[j * 256 + c];
        eemean[layer * 256 + c] = s;
    }
}

// scatter edges into dst-sorted order
__global__ void scatter_kernel(const int* __restrict__ src, const int* __restrict__ dst,
                               const int* __restrict__ offsets, int* __restrict__ cursors,
                               int* __restrict__ s_src, int* __restrict__ s_dst,
                               int* __restrict__ s_eid, int E)
{
    int stride = gridDim.x * blockDim.x;
    for (int e = blockIdx.x * blockDim.x + threadIdx.x; e < E; e += stride) {
        int d = dst[e];
        int p = offsets[d] + atomicAdd(&cursors[d], 1);
        s_src[p] = src[e];
        s_dst[p] = d;
        s_eid[p] = e;
    }
}

// ---------------------------------------------------------------------------
// all weight transposes (+ fused bias concat) in ONE launch. grid (8,12,8).
__global__ __launch_bounds__(256) void transpose_all_kernel(
    const float* __restrict__ W_in, const float* __restrict__ Wl0,
    const float* __restrict__ Wr0, const float* __restrict__ Wl1,
    const float* __restrict__ Wr1, const float* __restrict__ W_out,
    const float* __restrict__ We0, const float* __restrict__ We1,
    const float* __restrict__ bl0, const float* __restrict__ br0,
    const float* __restrict__ bl1, const float* __restrict__ br1,
    ushortT* __restrict__ WtIn, ushortT* __restrict__ WtLR0,
    ushortT* __restrict__ WtLR1, ushortT* __restrict__ WtOut,
    ushortT* __restrict__ Wet0, ushortT* __restrict__ Wet1,
    float* __restrict__ fb0, float* __restrict__ fb1)
{
    __shared__ float tile[32][33];
    int z = blockIdx.z;
    const float* in; ushortT* out; int K; const int N = 256;
    switch (z) {
        case 0: in = W_in;  out = WtIn;            K = 384; break;
        case 1: in = Wl0;   out = WtLR0;           K = 256; break;
        case 2: in = Wr0;   out = WtLR0 + 65536;   K = 256; break;
        case 3: in = Wl1;   out = WtLR1;           K = 256; break;
        case 4: in = Wr1;   out = WtLR1 + 65536;   K = 256; break;
        case 5: in = W_out; out = WtOut;           K = 256; break;
        case 6: in = We0;   out = Wet0;            K = 32;  break;
        default: in = We1;  out = Wet1;            K = 32;  break;
    }
    // fused bias concat on otherwise-idle blocks (z>=6, by==1)
    if (z >= 6 && blockIdx.y == 1) {
        if (blockIdx.x < 2) {
            int i = blockIdx.x * 256 + threadIdx.x;
            float v = (i < 256) ? ((z == 6) ? bl0[i] : bl1[i])
                                : ((z == 6) ? br0[i - 256] : br1[i - 256]);
            ((z == 6) ? fb0 : fb1)[i] = v;
        }
        return;
    }
    int by = blockIdx.y * 32;
    if (by >= K) return;
    int bx = blockIdx.x * 32;
    int tx = threadIdx.x & 31, ty = threadIdx.x >> 5;
#pragma unroll
    for (int r = 0; r < 32; r += 8) {
        int k = by + ty + r, n = bx + tx;
        if (k < K && n < N) tile[ty + r][tx] = in[(size_t)k * N + n];
    }
    __syncthreads();
#pragma unroll
    for (int r = 0; r < 32; r += 8) {
        int n = bx + ty + r, k = by + tx;
        if (n < N && k < K) out[(size_t)n * K + k] = f2bf(tile[tx][ty + r]);
    }
}

// ---------------------------------------------------------------------------
// MFMA bf16 GEMM: C[row,col] = act(A[row,:K] @ Bt[col,:K]^T + bias[col])
// A fp32 [>=Mvalid][K] (staged->bf16), Bt bf16 [Nn][K] (pre-transposed weights).
// 128x128 tile, BK=32, 256 threads = 4 waves (2x2), 16 mfma_16x16x32 per wave/step.
__global__ __launch_bounds__(256) void mfma_gemm_kernel(
    const float* __restrict__ A, const ushortT* __restrict__ Bt,
    const float* __restrict__ bias, float* __restrict__ Cf,
    ushortT* __restrict__ Cb, int K, int Nn, int act)
{
    __shared__ __align__(16) ushortT As[128 * 32];
    __shared__ __align__(16) ushortT Bs[128 * 32];
    int tid = threadIdx.x;
    int brow = blockIdx.x * 128;
    int bcol = blockIdx.y * 128;
    int lane = tid & 63, w = tid >> 6;
    int wr = w >> 1, wc = w & 1;
    int fr = lane & 15, fq = lane >> 4;

    f32x4 acc[4][4];
#pragma unroll
    for (int i = 0; i < 4; ++i)
#pragma unroll
        for (int j = 0; j < 4; ++j)
            acc[i][j] = (f32x4){0.f, 0.f, 0.f, 0.f};

    int r0 = tid >> 2, g0 = tid & 3;
    int r1 = r0 + 64;
    int arow0 = brow + r0, arow1 = brow + r1;
    bool av0 = arow0 < N_NODES, av1 = arow1 < N_NODES;
    const float* Ap0 = A + (size_t)arow0 * K + g0 * 8;
    const float* Ap1 = A + (size_t)arow1 * K + g0 * 8;
    const ushortT* Bp0 = Bt + (size_t)(bcol + r0) * K + g0 * 8;
    const ushortT* Bp1 = Bt + (size_t)(bcol + r1) * K + g0 * 8;
    uint4* asw0 = (uint4*)&As[(size_t)tid * 8];
    uint4* asw1 = (uint4*)&As[(size_t)(tid + 256) * 8];
    uint4* bsw0 = (uint4*)&Bs[(size_t)tid * 8];
    uint4* bsw1 = (uint4*)&Bs[(size_t)(tid + 256) * 8];

    for (int k0 = 0; k0 < K; k0 += 32) {
        float4 z = make_float4(0.f, 0.f, 0.f, 0.f);
        float4 fa0 = z, fa1 = z, fc0 = z, fc1 = z;
        if (av0) { fa0 = *(const float4*)(Ap0 + k0); fc0 = *(const float4*)(Ap0 + k0 + 4); }
        if (av1) { fa1 = *(const float4*)(Ap1 + k0); fc1 = *(const float4*)(Ap1 + k0 + 4); }
        uint4 ub0 = *(const uint4*)(Bp0 + k0);
        uint4 ub1 = *(const uint4*)(Bp1 + k0);
        uint4 ua0, ua1;
        ua0.x = pack2(fa0.x, fa0.y); ua0.y = pack2(fa0.z, fa0.w);
        ua0.z = pack2(fc0.x, fc0.y); ua0.w = pack2(fc0.z, fc0.w);
        ua1.x = pack2(fa1.x, fa1.y); ua1.y = pack2(fa1.z, fa1.w);
        ua1.z = pack2(fc1.x, fc1.y); ua1.w = pack2(fc1.z, fc1.w);
        __syncthreads();
        *asw0 = ua0; *asw1 = ua1;
        *bsw0 = ub0; *bsw1 = ub1;
        __syncthreads();

        bf16x8 af[4], bfv[4];
#pragma unroll
        for (int mi = 0; mi < 4; ++mi)
            af[mi] = *(bf16x8*)&As[(size_t)(wr * 64 + mi * 16 + fr) * 32 + fq * 8];
#pragma unroll
        for (int ni = 0; ni < 4; ++ni)
            bfv[ni] = *(bf16x8*)&Bs[(size_t)(wc * 64 + ni * 16 + fr) * 32 + fq * 8];
#pragma unroll
        for (int mi = 0; mi < 4; ++mi)
#pragma unroll
            for (int ni = 0; ni < 4; ++ni)
                acc[mi][ni] = __builtin_amdgcn_mfma_f32_16x16x32_bf16(
                    af[mi], bfv[ni], acc[mi][ni], 0, 0, 0);
    }

#pragma unroll
    for (int ni = 0; ni < 4; ++ni) {
        int col = bcol + wc * 64 + ni * 16 + fr;
        float bv = bias[col];
#pragma unroll
        for (int mi = 0; mi < 4; ++mi) {
#pragma unroll
            for (int r = 0; r < 4; ++r) {
                int row = brow + wr * 64 + mi * 16 + fq * 4 + r;
                if (row < N_NODES) {
                    float t = acc[mi][ni][r] + bv;
                    if (act == 1) t = t > 0.f ? t : 0.f;
                    if (Cf) Cf[(size_t)row * Nn + col] = t;
                    if (Cb) Cb[(size_t)row * Nn + col] = f2bf(t);
                }
            }
        }
    }
}

// ---------------------------------------------------------------------------
// MFMA edge logits, channel-permuted, 256 edges per block (4 sets of 16/wave).
// Wet staged so that MFMA tile mi, C-row j=fq*4+r holds actual channel
// ch = fq*64 + mi*4 + r  -> each lane's 64 channels are the contiguous block
// [fq*64, fq*64+64) = exactly head fq. Epilogue: 16B gathers, no shuffles.
__global__ __launch_bounds__(256) void edge_logits_kernel(
    const float* __restrict__ ea, const int* __restrict__ s_eid,
    const int* __restrict__ s_src, const int* __restrict__ s_dst,
    const ushortT* __restrict__ Wet, const float* __restrict__ att,
    const ushortT* __restrict__ xlr, float* __restrict__ logits)
{
    __shared__ __align__(16) ushortT Wet_lds[256 * 40];
    __shared__ float att_lds[256];
    __shared__ int sidx[256], didx[256], eidv[256];
    int tid = threadIdx.x;
    int brow = blockIdx.x * 256;

    // stage Wet permuted: staged row sr (tile mi = sr>>4, j = sr&15) holds
    // actual channel ch = (j>>2)*64 + mi*4 + (j&3); row stride 40 bf16.
#pragma unroll
    for (int t = 0; t < 4; ++t) {
        int f = tid + t * 256;
        int sr = f >> 2, q = f & 3;
        int mi = sr >> 4, j = sr & 15;
        int ch = ((j >> 2) << 6) + mi * 4 + (j & 3);
        *(uint4*)&Wet_lds[sr * 40 + q * 8] = *(const uint4*)(Wet + (size_t)ch * 32 + q * 8);
    }
    att_lds[tid] = att[tid];
    sidx[tid] = s_src[brow + tid];
    didx[tid] = s_dst[brow + tid];
    eidv[tid] = s_eid[brow + tid];
    __syncthreads();

    int lane = tid & 63, w = tid >> 6;
    int fr = lane & 15, fq = lane >> 4;
    const float* atp = &att_lds[fq * 64];

#pragma unroll
    for (int s4 = 0; s4 < 4; ++s4) {
        int e_lane = w * 64 + s4 * 16 + fr;

        // b-frag: this lane's edge ea row, floats fq*8..fq*8+7 -> bf16x8
        int eid = eidv[e_lane];
        const float* earow = ea + (size_t)eid * 32 + fq * 8;
        float4 f0 = ((const float4*)earow)[0];
        float4 f1 = ((const float4*)earow)[1];
        union { unsigned u[4]; bf16x8 v; } ub;
        ub.u[0] = pack2(f0.x, f0.y);
        ub.u[1] = pack2(f0.z, f0.w);
        ub.u[2] = pack2(f1.x, f1.y);
        ub.u[3] = pack2(f1.z, f1.w);
        bf16x8 bfrag = ub.v;

        f32x4 acc[16];
#pragma unroll
        for (int mi = 0; mi < 16; ++mi) {
            bf16x8 afrag = *(bf16x8*)&Wet_lds[(mi * 16 + fr) * 40 + fq * 8];
            acc[mi] = __builtin_amdgcn_mfma_f32_16x16x32_bf16(
                afrag, bfrag, (f32x4){0.f, 0.f, 0.f, 0.f}, 0, 0, 0);
        }

        // epilogue: lane owns channels [fq*64, fq*64+64) of its edge = head fq
        int sn = sidx[e_lane], dn = didx[e_lane];
        const ushortT* lxp = xlr + (size_t)sn * 512 + fq * 64;
        const ushortT* rxp = xlr + (size_t)dn * 512 + 256 + fq * 64;
        float lgsum = 0.f;
#pragma unroll
        for (int m2 = 0; m2 < 8; ++m2) {
            uint4 lu = *(const uint4*)(lxp + m2 * 8);
            uint4 ru = *(const uint4*)(rxp + m2 * 8);
            float lf[8], rf[8];
            unpack8(lu, lf);
            unpack8(ru, rf);
            float4 a0 = *(const float4*)(atp + m2 * 8);
            float4 a1 = *(const float4*)(atp + m2 * 8 + 4);
            f32x4 e0 = acc[2 * m2];
            f32x4 e1 = acc[2 * m2 + 1];
            float t0 = e0[0] + lf[0] + rf[0]; t0 = t0 > 0.f ? t0 : 0.2f * t0;
            float t1 = e0[1] + lf[1] + rf[1]; t1 = t1 > 0.f ? t1 : 0.2f * t1;
            float t2 = e0[2] + lf[2] + rf[2]; t2 = t2 > 0.f ? t2 : 0.2f * t2;
            float t3 = e0[3] + lf[3] + rf[3]; t3 = t3 > 0.f ? t3 : 0.2f * t3;
            float t4 = e1[0] + lf[4] + rf[4]; t4 = t4 > 0.f ? t4 : 0.2f * t4;
            float t5 = e1[1] + lf[5] + rf[5]; t5 = t5 > 0.f ? t5 : 0.2f * t5;
            float t6 = e1[2] + lf[6] + rf[6]; t6 = t6 > 0.f ? t6 : 0.2f * t6;
            float t7 = e1[3] + lf[7] + rf[7]; t7 = t7 > 0.f ? t7 : 0.2f * t7;
            lgsum += t0 * a0.x + t1 * a0.y + t2 * a0.z + t3 * a0.w
                   + t4 * a1.x + t5 * a1.y + t6 * a1.z + t7 * a1.w;
        }
        logits[(size_t)(brow + e_lane) * 4 + fq] = lgsum;
    }
}

// ---------------------------------------------------------------------------
// Fused attention (R5-proven structure): one wave per dst node, depth-1
// prefetch, per-edge online softmax; +bias, elu, h += hn; fused stats.
__global__ __launch_bounds__(256) void edge_attn_kernel(
    const int* __restrict__ s_src, const int* __restrict__ offsets,
    const float* __restrict__ logits,
    const float* __restrict__ att, const float* __restrict__ bias,
    const float* __restrict__ eemean,
    const ushortT* __restrict__ xlr, float* __restrict__ h,
    float* __restrict__ stats)
{
    int lane = threadIdx.x & 63;
    int wv = threadIdx.x >> 6;
    int d = blockIdx.x * 4 + wv;
    size_t xbase = (size_t)d * 512 + lane * 4;
    size_t hbase = (size_t)d * 256 + lane * 4;
    int head = lane >> 4;

    ushort4 xlu = *(const ushort4*)(xlr + xbase);
    ushort4 xru = *(const ushort4*)(xlr + xbase + 256);
    float xr0 = bf2f(xru.x), xr1 = bf2f(xru.y), xr2 = bf2f(xru.z), xr3 = bf2f(xru.w);
    float xs0 = bf2f(xlu.x), xs1 = bf2f(xlu.y), xs2 = bf2f(xlu.z), xs3 = bf2f(xlu.w);
    float4 eem = *(const float4*)(eemean + lane * 4);
    float4 at4 = *(const float4*)(att + lane * 4);

    float m = -1e30f, s = 0.f;
    float acc0 = 0.f, acc1 = 0.f, acc2 = 0.f, acc3 = 0.f;
    int beg = offsets[d], end = offsets[d + 1];

    int idx1 = 0;
    ushort4 x_cur = make_ushort4(0, 0, 0, 0);
    float lg_cur = 0.f;
    if (beg < end) {
        int idx0 = s_src[beg];
        x_cur = *(const ushort4*)(xlr + (size_t)idx0 * 512 + lane * 4);
        lg_cur = logits[(size_t)beg * 4 + head];
        if (beg + 1 < end) idx1 = s_src[beg + 1];
    }

    for (int pos = beg; pos < end; ++pos) {
        ushort4 xv = x_cur;
        float lg = lg_cur;
        int np = pos + 1;
        if (np < end) {
            x_cur = *(const ushort4*)(xlr + (size_t)idx1 * 512 + lane * 4);
            lg_cur = logits[(size_t)np * 4 + head];
        }
        if (pos + 2 < end) idx1 = s_src[pos + 2];

        float nm = fmaxf(m, lg);
        float sc = __expf(m - nm);
        float pr = __expf(lg - nm);
        float v0 = bf2f(xv.x), v1 = bf2f(xv.y), v2 = bf2f(xv.z), v3 = bf2f(xv.w);
        s = s * sc + pr;
        acc0 = acc0 * sc + pr * v0;
        acc1 = acc1 * sc + pr * v1;
        acc2 = acc2 * sc + pr * v2;
        acc3 = acc3 * sc + pr * v3;
        m = nm;
    }

    // self-loop edge (xl[d], eemean)
    {
        float t0 = xs0 + xr0 + eem.x; t0 = t0 > 0.f ? t0 : 0.2f * t0;
        float t1 = xs1 + xr1 + eem.y; t1 = t1 > 0.f ? t1 : 0.2f * t1;
        float t2 = xs2 + xr2 + eem.z; t2 = t2 > 0.f ? t2 : 0.2f * t2;
        float t3 = xs3 + xr3 + eem.w; t3 = t3 > 0.f ? t3 : 0.2f * t3;
        float lg = t0 * at4.x + t1 * at4.y + t2 * at4.z + t3 * at4.w;
        lg += __shfl_xor(lg, 1);
        lg += __shfl_xor(lg, 2);
        lg += __shfl_xor(lg, 4);
        lg += __shfl_xor(lg, 8);        // 16-lane head group holds the logit
        float nm = fmaxf(m, lg);
        float sc = __expf(m - nm);
        float pr = __expf(lg - nm);
        s = s * sc + pr;
        acc0 = acc0 * sc + pr * xs0;
        acc1 = acc1 * sc + pr * xs1;
        acc2 = acc2 * sc + pr * xs2;
        acc3 = acc3 * sc + pr * xs3;
    }

    float inv = 1.f / s;
    float4 b4 = *(const float4*)(bias + lane * 4);
    float4 hv = *(const float4*)(h + hbase);
    float o0 = acc0 * inv + b4.x; o0 = o0 > 0.f ? o0 : __expf(o0) - 1.f;
    float o1 = acc1 * inv + b4.y; o1 = o1 > 0.f ? o1 : __expf(o1) - 1.f;
    float o2 = acc2 * inv + b4.z; o2 = o2 > 0.f ? o2 : __expf(o2) - 1.f;
    float o3 = acc3 * inv + b4.w; o3 = o3 > 0.f ? o3 : __expf(o3) - 1.f;
    float y0 = hv.x + o0, y1 = hv.y + o1, y2 = hv.z + o2, y3 = hv.w + o3;
    *(float4*)(h + hbase) = make_float4(y0, y1, y2, y3);

    // fused graph-norm stats
    float ls = y0 + y1 + y2 + y3;
    float lq = y0 * y0 + y1 * y1 + y2 * y2 + y3 * y3;
#pragma unroll
    for (int o = 1; o < 64; o <<= 1) {
        ls += __shfl_xor(ls, o);
        lq += __shfl_xor(lq, o);
    }
    __shared__ float red[8];
    if (lane == 0) { red[wv * 2] = ls; red[wv * 2 + 1] = lq; }
    __syncthreads();
    if (threadIdx.x == 0) {
        atomicAdd(&stats[0], red[0] + red[2] + red[4] + red[6]);
        atomicAdd(&stats[1], red[1] + red[3] + red[5] + red[7]);
    }
}

// ---------------------------------------------------------------------------
// h = (h - mu) * scale * g[k] + beta[k], in place; mu/scale computed inline
__global__ void normalize_kernel(float* __restrict__ h, const float* __restrict__ g,
                                 const float* __restrict__ beta, const float* __restrict__ stats)
{
    float invM = 1.f / ((float)N_NODES * 256.f);
    float mu = stats[0] * invM;
    float var = stats[1] * invM - mu * mu;
    float sc = rsqrtf(var + EPSN);
    int stride = gridDim.x * blockDim.x;
    int total = N_NODES * 64;      // float4 count
    for (int i = blockIdx.x * blockDim.x + threadIdx.x; i < total; i += stride) {
        float4 v = ((float4*)h)[i];
        int k = (i & 63) * 4;
        float4 gv = *(const float4*)&g[k];
        float4 bv = *(const float4*)&beta[k];
        v.x = (v.x - mu) * sc * gv.x + bv.x;
        v.y = (v.y - mu) * sc * gv.y + bv.y;
        v.z = (v.z - mu) * sc * gv.z + bv.z;
        v.w = (v.w - mu) * sc * gv.w + bv.w;
        ((float4*)h)[i] = v;
    }
}

// ---------------------------------------------------------------------------
extern "C" void kernel_launch(void* const* d_in, const int* in_sizes, int n_in,
                              void* d_out, int out_size, void* d_ws, size_t ws_size,
                              hipStream_t stream)
{
    (void)in_sizes; (void)n_in; (void)out_size; (void)ws_size;
    const float* x     = (const float*)d_in[0];
    const int*   eidx  = (const int*)d_in[1];
    const float* ea    = (const float*)d_in[2];
    const float* W_in  = (const float*)d_in[3];
    const float* b_in  = (const float*)d_in[4];
    const float* W_out = (const float*)d_in[5];
    const float* b_out = (const float*)d_in[6];
    const float* Wl[2]  = {(const float*)d_in[7],  (const float*)d_in[16]};
    const float* bl[2]  = {(const float*)d_in[8],  (const float*)d_in[17]};
    const float* Wr[2]  = {(const float*)d_in[9],  (const float*)d_in[18]};
    const float* br[2]  = {(const float*)d_in[10], (const float*)d_in[19]};
    const float* We[2]  = {(const float*)d_in[11], (const float*)d_in[20]};
    const float* att[2] = {(const float*)d_in[12], (const float*)d_in[21]};
    const float* bias[2]= {(const float*)d_in[13], (const float*)d_in[22]};
    const float* g[2]   = {(const float*)d_in[14], (const float*)d_in[23]};
    const float* beta[2]= {(const float*)d_in[15], (const float*)d_in[24]};

    // workspace layout (~127 MB)
    char* p = (char*)d_ws;
    auto take = [&](size_t bytes) -> char* {
        char* r = p;
        p += (bytes + 255) & ~(size_t)255;
        return r;
    };
    int*   counts  = (int*)take((size_t)N_NODES * 4);
    int*   cursors = (int*)take((size_t)N_NODES * 4);
    float* ea_acc  = (float*)take(32 * 4);
    float* stats   = (float*)take(8 * 4);
    size_t zero_bytes = (size_t)(p - (char*)d_ws);
    int*   offsets = (int*)take((size_t)(N_NODES + 1) * 4);
    int*   s_src   = (int*)take((size_t)E_EDGES * 4);
    int*   s_dst   = (int*)take((size_t)E_EDGES * 4);
    int*   s_eid   = (int*)take((size_t)E_EDGES * 4);
    float* eemean  = (float*)take(512 * 4);
    ushortT* WtIn  = (ushortT*)take((size_t)256 * 384 * 2);
    ushortT* WtLR0 = (ushortT*)take((size_t)512 * 256 * 2);
    ushortT* WtLR1 = (ushortT*)take((size_t)512 * 256 * 2);
    ushortT* WtOut = (ushortT*)take((size_t)256 * 256 * 2);
    ushortT* Wet0  = (ushortT*)take((size_t)256 * 32 * 2);
    ushortT* Wet1  = (ushortT*)take((size_t)256 * 32 * 2);
    float* fb0     = (float*)take(512 * 4);
    float* fb1     = (float*)take(512 * 4);
    ushortT* xlr   = (ushortT*)take((size_t)N_NODES * 512 * 2);
    float* h       = (float*)take((size_t)N_NODES * 256 * 4);
    float* logits  = (float*)take((size_t)E_EDGES * 4 * 4);

    const ushortT* WtLR[2] = {WtLR0, WtLR1};
    const ushortT* Wet[2] = {Wet0, Wet1};
    const float* fb[2] = {fb0, fb1};

    const int* srcv = eidx;
    const int* dstv = eidx + E_EDGES;

    hipMemsetAsync(d_ws, 0, zero_bytes, stream);

    prep_kernel<<<1024, 256, 0, stream>>>(ea, ea_acc, dstv, counts);
    scan_eemean_kernel<<<1, 1024, 0, stream>>>(counts, offsets, ea_acc, We[0], We[1],
                                               eemean, 1.0f / (float)E_EDGES);
    scatter_kernel<<<1024, 256, 0, stream>>>(srcv, dstv, offsets, cursors,
                                             s_src, s_dst, s_eid, E_EDGES);
    transpose_all_kernel<<<dim3(8, 12, 8), 256, 0, stream>>>(
        W_in, Wl[0], Wr[0], Wl[1], Wr[1], W_out, We[0], We[1],
        bl[0], br[0], bl[1], br[1],
        WtIn, WtLR0, WtLR1, WtOut, Wet0, Wet1, fb0, fb1);

    // h0 = relu(x @ W_in + b_in), fp32
    mfma_gemm_kernel<<<dim3(391, 2), 256, 0, stream>>>(x, WtIn, b_in, h, nullptr, 384, 256, 1);

    for (int l = 0; l < 2; ++l) {
        // fused [xl|xr] = h @ [Wl|Wr] + [bl|br], bf16 packed
        mfma_gemm_kernel<<<dim3(391, 4), 256, 0, stream>>>(h, WtLR[l], fb[l], nullptr, xlr,
                                                           256, 512, 0);
        edge_logits_kernel<<<E_EDGES / 256, 256, 0, stream>>>(ea, s_eid, s_src, s_dst,
                                                              Wet[l], att[l], xlr, logits);
        edge_attn_kernel<<<N_NODES / 4, 256, 0, stream>>>(s_src, offsets, logits,
                                                          att[l], bias[l], eemean + l * 256,
                                                          xlr, h, stats + l * 4);
        normalize_kernel<<<2048, 256, 0, stream>>>(h, g[l], beta[l], stats + l * 4);
    }
    // out = h @ W_out + b_out, fp32
    mfma_gemm_kernel<<<dim3(391, 2), 256, 0, stream>>>(h, WtOut, b_out, (float*)d_out, nullptr,
                                                       256, 256, 0);
}

// Round 9
// 1262.994 us; speedup vs baseline: 1.3632x; 1.2853x over previous
//
#include <hip/hip_runtime.h>
#include <hip/hip_bf16.h>

// Problem constants (from reference)
#define N_NODES 50000
#define E_EDGES 800000
#define DIN_K   384
#define DH_N    256
#define EPSN    1e-5f

typedef unsigned short ushortT;
typedef __attribute__((ext_vector_type(4))) float f32x4;
typedef __attribute__((ext_vector_type(8))) short bf16x8;

static __device__ __forceinline__ float bf2f(unsigned short u)
{
    return __uint_as_float(((unsigned)u) << 16);
}
static __device__ __forceinline__ unsigned short f2bf(float f)
{
    unsigned u = __float_as_uint(f);
    unsigned r = (u + 0x7fffu + ((u >> 16) & 1u)) >> 16;   // round-nearest-even
    return (unsigned short)r;
}
static __device__ __forceinline__ unsigned pack2(float a, float b)
{
    return (unsigned)f2bf(a) | ((unsigned)f2bf(b) << 16);
}
static __device__ __forceinline__ void unpack8(uint4 u, float* f)
{
    f[0] = bf2f((ushortT)(u.x & 0xffff)); f[1] = bf2f((ushortT)(u.x >> 16));
    f[2] = bf2f((ushortT)(u.y & 0xffff)); f[3] = bf2f((ushortT)(u.y >> 16));
    f[4] = bf2f((ushortT)(u.z & 0xffff)); f[5] = bf2f((ushortT)(u.z >> 16));
    f[6] = bf2f((ushortT)(u.w & 0xffff)); f[7] = bf2f((ushortT)(u.w >> 16));
}

// ---------------------------------------------------------------------------
// combined prep: edge_attr column sums + dst histogram (one launch)
__global__ __launch_bounds__(256) void prep_kernel(const float* __restrict__ ea,
                                                   float* __restrict__ accum,
                                                   const int* __restrict__ dst,
                                                   int* __restrict__ counts)
{
    int gstride = gridDim.x * blockDim.x;
    long total = (long)E_EDGES * 32;
    float local = 0.f;
    for (long i = (long)blockIdx.x * blockDim.x + threadIdx.x; i < total; i += gstride)
        local += ea[i];
    __shared__ float red[256];
    red[threadIdx.x] = local;
    __syncthreads();
    if (threadIdx.x < 32) {
        float s = 0.f;
#pragma unroll
        for (int r = 0; r < 8; ++r) s += red[r * 32 + threadIdx.x];
        atomicAdd(&accum[threadIdx.x], s);
    }
    for (int e = blockIdx.x * blockDim.x + threadIdx.x; e < E_EDGES; e += gstride)
        atomicAdd(&counts[dst[e]], 1);
}

// exclusive scan of counts -> offsets[N+1] (wave-shuffle scan, 2 barriers/chunk)
// + eemean tail: eemean[layer] = (mean ea) @ We_layer
__global__ __launch_bounds__(1024) void scan_eemean_kernel(
    const int* __restrict__ counts, int* __restrict__ offsets,
    const float* __restrict__ ea_acc, const float* __restrict__ We0,
    const float* __restrict__ We1, float* __restrict__ eemean, float invE)
{
    __shared__ int wtot[16];
    int tid = threadIdx.x, lane = tid & 63, wv = tid >> 6;
    int run = 0;
    for (int base = 0; base < N_NODES; base += 1024) {
        int i = base + tid;
        int v = (i < N_NODES) ? counts[i] : 0;
        int sc = v;
#pragma unroll
        for (int off = 1; off < 64; off <<= 1) {
            int t = __shfl_up(sc, off);
            if (lane >= off) sc += t;
        }
        if (lane == 63) wtot[wv] = sc;
        __syncthreads();
        int wpre = 0, tot = 0;
#pragma unroll
        for (int k = 0; k < 16; ++k) {
            int t = wtot[k];
            if (k < wv) wpre += t;
            tot += t;
        }
        if (i < N_NODES) offsets[i] = run + wpre + sc - v;   // exclusive
        run += tot;
        __syncthreads();
    }
    if (tid == 0) offsets[N_NODES] = run;
    // eemean tail
    if (tid < 512) {
        int layer = tid >> 8, c = tid & 255;
        const float* W = layer ? We1 : We0;
        float s = 0.f;
#pragma unroll
        for (int j = 0; j < 32; ++j) s += ea_acc[j] * invE * W[j * 256 + c];
        eemean[layer * 256 + c] = s;
    }
}

// scatter edges into dst-sorted order
__global__ void scatter_kernel(const int* __restrict__ src, const int* __restrict__ dst,
                               const int* __restrict__ offsets, int* __restrict__ cursors,
                               int* __restrict__ s_src, int* __restrict__ s_dst,
                               int* __restrict__ s_eid, int E)
{
    int stride = gridDim.x * blockDim.x;
    for (int e = blockIdx.x * blockDim.x + threadIdx.x; e < E; e += stride) {
        int d = dst[e];
        int p = offsets[d] + atomicAdd(&cursors[d], 1);
        s_src[p] = src[e];
        s_dst[p] = d;
        s_eid[p] = e;
    }
}

// ---------------------------------------------------------------------------
// all weight transposes (+ fused bias concat) in ONE launch. grid (8,12,8).
__global__ __launch_bounds__(256) void transpose_all_kernel(
    const float* __restrict__ W_in, const float* __restrict__ Wl0,
    const float* __restrict__ Wr0, const float* __restrict__ Wl1,
    const float* __restrict__ Wr1, const float* __restrict__ W_out,
    const float* __restrict__ We0, const float* __restrict__ We1,
    const float* __restrict__ bl0, const float* __restrict__ br0,
    const float* __restrict__ bl1, const float* __restrict__ br1,
    ushortT* __restrict__ WtIn, ushortT* __restrict__ WtLR0,
    ushortT* __restrict__ WtLR1, ushortT* __restrict__ WtOut,
    ushortT* __restrict__ Wet0, ushortT* __restrict__ Wet1,
    float* __restrict__ fb0, float* __restrict__ fb1)
{
    __shared__ float tile[32][33];
    int z = blockIdx.z;
    const float* in; ushortT* out; int K; const int N = 256;
    switch (z) {
        case 0: in = W_in;  out = WtIn;            K = 384; break;
        case 1: in = Wl0;   out = WtLR0;           K = 256; break;
        case 2: in = Wr0;   out = WtLR0 + 65536;   K = 256; break;
        case 3: in = Wl1;   out = WtLR1;           K = 256; break;
        case 4: in = Wr1;   out = WtLR1 + 65536;   K = 256; break;
        case 5: in = W_out; out = WtOut;           K = 256; break;
        case 6: in = We0;   out = Wet0;            K = 32;  break;
        default: in = We1;  out = Wet1;            K = 32;  break;
    }
    // fused bias concat on otherwise-idle blocks (z>=6, by==1)
    if (z >= 6 && blockIdx.y == 1) {
        if (blockIdx.x < 2) {
            int i = blockIdx.x * 256 + threadIdx.x;
            float v = (i < 256) ? ((z == 6) ? bl0[i] : bl1[i])
                                : ((z == 6) ? br0[i - 256] : br1[i - 256]);
            ((z == 6) ? fb0 : fb1)[i] = v;
        }
        return;
    }
    int by = blockIdx.y * 32;
    if (by >= K) return;
    int bx = blockIdx.x * 32;
    int tx = threadIdx.x & 31, ty = threadIdx.x >> 5;
#pragma unroll
    for (int r = 0; r < 32; r += 8) {
        int k = by + ty + r, n = bx + tx;
        if (k < K && n < N) tile[ty + r][tx] = in[(size_t)k * N + n];
    }
    __syncthreads();
#pragma unroll
    for (int r = 0; r < 32; r += 8) {
        int n = bx + ty + r, k = by + tx;
        if (n < N && k < K) out[(size_t)n * K + k] = f2bf(tile[tx][ty + r]);
    }
}

// ---------------------------------------------------------------------------
// MFMA bf16 GEMM: C[row,col] = act(A[row,:K] @ Bt[col,:K]^T + bias[col])
// A fp32 [>=Mvalid][K] (staged->bf16), Bt bf16 [Nn][K] (pre-transposed weights).
// 128x128 tile, BK=32, 256 threads = 4 waves (2x2), 16 mfma_16x16x32 per wave/step.
__global__ __launch_bounds__(256) void mfma_gemm_kernel(
    const float* __restrict__ A, const ushortT* __restrict__ Bt,
    const float* __restrict__ bias, float* __restrict__ Cf,
    ushortT* __restrict__ Cb, int K, int Nn, int act)
{
    __shared__ __align__(16) ushortT As[128 * 32];
    __shared__ __align__(16) ushortT Bs[128 * 32];
    int tid = threadIdx.x;
    int brow = blockIdx.x * 128;
    int bcol = blockIdx.y * 128;
    int lane = tid & 63, w = tid >> 6;
    int wr = w >> 1, wc = w & 1;
    int fr = lane & 15, fq = lane >> 4;

    f32x4 acc[4][4];
#pragma unroll
    for (int i = 0; i < 4; ++i)
#pragma unroll
        for (int j = 0; j < 4; ++j)
            acc[i][j] = (f32x4){0.f, 0.f, 0.f, 0.f};

    int r0 = tid >> 2, g0 = tid & 3;
    int r1 = r0 + 64;
    int arow0 = brow + r0, arow1 = brow + r1;
    bool av0 = arow0 < N_NODES, av1 = arow1 < N_NODES;
    const float* Ap0 = A + (size_t)arow0 * K + g0 * 8;
    const float* Ap1 = A + (size_t)arow1 * K + g0 * 8;
    const ushortT* Bp0 = Bt + (size_t)(bcol + r0) * K + g0 * 8;
    const ushortT* Bp1 = Bt + (size_t)(bcol + r1) * K + g0 * 8;
    uint4* asw0 = (uint4*)&As[(size_t)tid * 8];
    uint4* asw1 = (uint4*)&As[(size_t)(tid + 256) * 8];
    uint4* bsw0 = (uint4*)&Bs[(size_t)tid * 8];
    uint4* bsw1 = (uint4*)&Bs[(size_t)(tid + 256) * 8];

    for (int k0 = 0; k0 < K; k0 += 32) {
        float4 z = make_float4(0.f, 0.f, 0.f, 0.f);
        float4 fa0 = z, fa1 = z, fc0 = z, fc1 = z;
        if (av0) { fa0 = *(const float4*)(Ap0 + k0); fc0 = *(const float4*)(Ap0 + k0 + 4); }
        if (av1) { fa1 = *(const float4*)(Ap1 + k0); fc1 = *(const float4*)(Ap1 + k0 + 4); }
        uint4 ub0 = *(const uint4*)(Bp0 + k0);
        uint4 ub1 = *(const uint4*)(Bp1 + k0);
        uint4 ua0, ua1;
        ua0.x = pack2(fa0.x, fa0.y); ua0.y = pack2(fa0.z, fa0.w);
        ua0.z = pack2(fc0.x, fc0.y); ua0.w = pack2(fc0.z, fc0.w);
        ua1.x = pack2(fa1.x, fa1.y); ua1.y = pack2(fa1.z, fa1.w);
        ua1.z = pack2(fc1.x, fc1.y); ua1.w = pack2(fc1.z, fc1.w);
        __syncthreads();
        *asw0 = ua0; *asw1 = ua1;
        *bsw0 = ub0; *bsw1 = ub1;
        __syncthreads();

        bf16x8 af[4], bfv[4];
#pragma unroll
        for (int mi = 0; mi < 4; ++mi)
            af[mi] = *(bf16x8*)&As[(size_t)(wr * 64 + mi * 16 + fr) * 32 + fq * 8];
#pragma unroll
        for (int ni = 0; ni < 4; ++ni)
            bfv[ni] = *(bf16x8*)&Bs[(size_t)(wc * 64 + ni * 16 + fr) * 32 + fq * 8];
#pragma unroll
        for (int mi = 0; mi < 4; ++mi)
#pragma unroll
            for (int ni = 0; ni < 4; ++ni)
                acc[mi][ni] = __builtin_amdgcn_mfma_f32_16x16x32_bf16(
                    af[mi], bfv[ni], acc[mi][ni], 0, 0, 0);
    }

#pragma unroll
    for (int ni = 0; ni < 4; ++ni) {
        int col = bcol + wc * 64 + ni * 16 + fr;
        float bv = bias[col];
#pragma unroll
        for (int mi = 0; mi < 4; ++mi) {
#pragma unroll
            for (int r = 0; r < 4; ++r) {
                int row = brow + wr * 64 + mi * 16 + fq * 4 + r;
                if (row < N_NODES) {
                    float t = acc[mi][ni][r] + bv;
                    if (act == 1) t = t > 0.f ? t : 0.f;
                    if (Cf) Cf[(size_t)row * Nn + col] = t;
                    if (Cb) Cb[(size_t)row * Nn + col] = f2bf(t);
                }
            }
        }
    }
}

// ---------------------------------------------------------------------------
// MFMA edge logits, channel-permuted, 256 edges per block (4 sets of 16/wave).
// Wet staged so that MFMA tile mi, C-row j=fq*4+r holds actual channel
// ch = fq*64 + mi*4 + r  -> each lane's 64 channels are the contiguous block
// [fq*64, fq*64+64) = exactly head fq. Epilogue: 16B gathers, no shuffles.
__global__ __launch_bounds__(256) void edge_logits_kernel(
    const float* __restrict__ ea, const int* __restrict__ s_eid,
    const int* __restrict__ s_src, const int* __restrict__ s_dst,
    const ushortT* __restrict__ Wet, const float* __restrict__ att,
    const ushortT* __restrict__ xlr, float* __restrict__ logits)
{
    __shared__ __align__(16) ushortT Wet_lds[256 * 40];
    __shared__ float att_lds[256];
    __shared__ int sidx[256], didx[256], eidv[256];
    int tid = threadIdx.x;
    int brow = blockIdx.x * 256;

    // stage Wet permuted: staged row sr (tile mi = sr>>4, j = sr&15) holds
    // actual channel ch = (j>>2)*64 + mi*4 + (j&3); row stride 40 bf16.
#pragma unroll
    for (int t = 0; t < 4; ++t) {
        int f = tid + t * 256;
        int sr = f >> 2, q = f & 3;
        int mi = sr >> 4, j = sr & 15;
        int ch = ((j >> 2) << 6) + mi * 4 + (j & 3);
        *(uint4*)&Wet_lds[sr * 40 + q * 8] = *(const uint4*)(Wet + (size_t)ch * 32 + q * 8);
    }
    att_lds[tid] = att[tid];
    sidx[tid] = s_src[brow + tid];
    didx[tid] = s_dst[brow + tid];
    eidv[tid] = s_eid[brow + tid];
    __syncthreads();

    int lane = tid & 63, w = tid >> 6;
    int fr = lane & 15, fq = lane >> 4;
    const float* atp = &att_lds[fq * 64];

#pragma unroll
    for (int s4 = 0; s4 < 4; ++s4) {
        int e_lane = w * 64 + s4 * 16 + fr;

        // b-frag: this lane's edge ea row, floats fq*8..fq*8+7 -> bf16x8
        int eid = eidv[e_lane];
        const float* earow = ea + (size_t)eid * 32 + fq * 8;
        float4 f0 = ((const float4*)earow)[0];
        float4 f1 = ((const float4*)earow)[1];
        union { unsigned u[4]; bf16x8 v; } ub;
        ub.u[0] = pack2(f0.x, f0.y);
        ub.u[1] = pack2(f0.z, f0.w);
        ub.u[2] = pack2(f1.x, f1.y);
        ub.u[3] = pack2(f1.z, f1.w);
        bf16x8 bfrag = ub.v;

        f32x4 acc[16];
#pragma unroll
        for (int mi = 0; mi < 16; ++mi) {
            bf16x8 afrag = *(bf16x8*)&Wet_lds[(mi * 16 + fr) * 40 + fq * 8];
            acc[mi] = __builtin_amdgcn_mfma_f32_16x16x32_bf16(
                afrag, bfrag, (f32x4){0.f, 0.f, 0.f, 0.f}, 0, 0, 0);
        }

        // epilogue: lane owns channels [fq*64, fq*64+64) of its edge = head fq
        int sn = sidx[e_lane], dn = didx[e_lane];
        const ushortT* lxp = xlr + (size_t)sn * 512 + fq * 64;
        const ushortT* rxp = xlr + (size_t)dn * 512 + 256 + fq * 64;
        float lgsum = 0.f;
#pragma unroll
        for (int m2 = 0; m2 < 8; ++m2) {
            uint4 lu = *(const uint4*)(lxp + m2 * 8);
            uint4 ru = *(const uint4*)(rxp + m2 * 8);
            float lf[8], rf[8];
            unpack8(lu, lf);
            unpack8(ru, rf);
            float4 a0 = *(const float4*)(atp + m2 * 8);
            float4 a1 = *(const float4*)(atp + m2 * 8 + 4);
            f32x4 e0 = acc[2 * m2];
            f32x4 e1 = acc[2 * m2 + 1];
            float t0 = e0[0] + lf[0] + rf[0]; t0 = t0 > 0.f ? t0 : 0.2f * t0;
            float t1 = e0[1] + lf[1] + rf[1]; t1 = t1 > 0.f ? t1 : 0.2f * t1;
            float t2 = e0[2] + lf[2] + rf[2]; t2 = t2 > 0.f ? t2 : 0.2f * t2;
            float t3 = e0[3] + lf[3] + rf[3]; t3 = t3 > 0.f ? t3 : 0.2f * t3;
            float t4 = e1[0] + lf[4] + rf[4]; t4 = t4 > 0.f ? t4 : 0.2f * t4;
            float t5 = e1[1] + lf[5] + rf[5]; t5 = t5 > 0.f ? t5 : 0.2f * t5;
            float t6 = e1[2] + lf[6] + rf[6]; t6 = t6 > 0.f ? t6 : 0.2f * t6;
            float t7 = e1[3] + lf[7] + rf[7]; t7 = t7 > 0.f ? t7 : 0.2f * t7;
            lgsum += t0 * a0.x + t1 * a0.y + t2 * a0.z + t3 * a0.w
                   + t4 * a1.x + t5 * a1.y + t6 * a1.z + t7 * a1.w;
        }
        logits[(size_t)(brow + e_lane) * 4 + fq] = lgsum;
    }
}

// ---------------------------------------------------------------------------
// Fused attention — EXACT R5 kernel (byte-for-byte): one wave per dst node,
// depth-1 prefetch, per-edge online softmax, +bias, elu, h += hn in place.
// NOTE: no stats fusion here — adding the LDS+barrier epilogue in R8 made the
// compiler drop to 24 VGPRs and de-pipeline the gather loop (340us vs ~150us).
__global__ __launch_bounds__(256) void edge_attn_kernel(
    const int* __restrict__ s_src, const int* __restrict__ offsets,
    const float* __restrict__ logits,
    const float* __restrict__ att, const float* __restrict__ bias,
    const float* __restrict__ eemean,
    const ushortT* __restrict__ xlr, float* __restrict__ h)
{
    int lane = threadIdx.x & 63;
    int d = blockIdx.x * 4 + (threadIdx.x >> 6);
    size_t xbase = (size_t)d * 512 + lane * 4;
    size_t hbase = (size_t)d * 256 + lane * 4;
    int head = lane >> 4;

    ushort4 xlu = *(const ushort4*)(xlr + xbase);
    ushort4 xru = *(const ushort4*)(xlr + xbase + 256);
    float xr0 = bf2f(xru.x), xr1 = bf2f(xru.y), xr2 = bf2f(xru.z), xr3 = bf2f(xru.w);
    float xs0 = bf2f(xlu.x), xs1 = bf2f(xlu.y), xs2 = bf2f(xlu.z), xs3 = bf2f(xlu.w);
    float4 eem = *(const float4*)(eemean + lane * 4);
    float4 at4 = *(const float4*)(att + lane * 4);

    float m = -1e30f, s = 0.f;
    float acc0 = 0.f, acc1 = 0.f, acc2 = 0.f, acc3 = 0.f;
    int beg = offsets[d], end = offsets[d + 1];

    int idx1 = 0;
    ushort4 x_cur = make_ushort4(0, 0, 0, 0);
    float lg_cur = 0.f;
    if (beg < end) {
        int idx0 = s_src[beg];
        x_cur = *(const ushort4*)(xlr + (size_t)idx0 * 512 + lane * 4);
        lg_cur = logits[(size_t)beg * 4 + head];
        if (beg + 1 < end) idx1 = s_src[beg + 1];
    }

    for (int pos = beg; pos < end; ++pos) {
        ushort4 xv = x_cur;
        float lg = lg_cur;
        int np = pos + 1;
        if (np < end) {
            x_cur = *(const ushort4*)(xlr + (size_t)idx1 * 512 + lane * 4);
            lg_cur = logits[(size_t)np * 4 + head];
        }
        if (pos + 2 < end) idx1 = s_src[pos + 2];

        float nm = fmaxf(m, lg);
        float sc = __expf(m - nm);
        float pr = __expf(lg - nm);
        float v0 = bf2f(xv.x), v1 = bf2f(xv.y), v2 = bf2f(xv.z), v3 = bf2f(xv.w);
        s = s * sc + pr;
        acc0 = acc0 * sc + pr * v0;
        acc1 = acc1 * sc + pr * v1;
        acc2 = acc2 * sc + pr * v2;
        acc3 = acc3 * sc + pr * v3;
        m = nm;
    }

    // self-loop edge (xl[d], eemean)
    {
        float t0 = xs0 + xr0 + eem.x; t0 = t0 > 0.f ? t0 : 0.2f * t0;
        float t1 = xs1 + xr1 + eem.y; t1 = t1 > 0.f ? t1 : 0.2f * t1;
        float t2 = xs2 + xr2 + eem.z; t2 = t2 > 0.f ? t2 : 0.2f * t2;
        float t3 = xs3 + xr3 + eem.w; t3 = t3 > 0.f ? t3 : 0.2f * t3;
        float lg = t0 * at4.x + t1 * at4.y + t2 * at4.z + t3 * at4.w;
        lg += __shfl_xor(lg, 1);
        lg += __shfl_xor(lg, 2);
        lg += __shfl_xor(lg, 4);
        lg += __shfl_xor(lg, 8);        // 16-lane head group holds the logit
        float nm = fmaxf(m, lg);
        float sc = __expf(m - nm);
        float pr = __expf(lg - nm);
        s = s * sc + pr;
        acc0 = acc0 * sc + pr * xs0;
        acc1 = acc1 * sc + pr * xs1;
        acc2 = acc2 * sc + pr * xs2;
        acc3 = acc3 * sc + pr * xs3;
    }

    float inv = 1.f / s;
    float4 b4 = *(const float4*)(bias + lane * 4);
    float4 hv = *(const float4*)(h + hbase);
    float o0 = acc0 * inv + b4.x; o0 = o0 > 0.f ? o0 : __expf(o0) - 1.f;
    float o1 = acc1 * inv + b4.y; o1 = o1 > 0.f ? o1 : __expf(o1) - 1.f;
    float o2 = acc2 * inv + b4.z; o2 = o2 > 0.f ? o2 : __expf(o2) - 1.f;
    float o3 = acc3 * inv + b4.w; o3 = o3 > 0.f ? o3 : __expf(o3) - 1.f;
    *(float4*)(h + hbase) = make_float4(hv.x + o0, hv.y + o1, hv.z + o2, hv.w + o3);
}

// ---------------------------------------------------------------------------
// graph-norm stats: sum and sumsq of h, one atomic pair per block
__global__ __launch_bounds__(256) void stats_kernel(const float* __restrict__ h,
                                                    float* __restrict__ stats)
{
    int stride = gridDim.x * blockDim.x;
    int total = N_NODES * 64;      // float4 count
    float ls = 0.f, lq = 0.f;
    for (int i = blockIdx.x * blockDim.x + threadIdx.x; i < total; i += stride) {
        float4 v = ((const float4*)h)[i];
        ls += v.x + v.y + v.z + v.w;
        lq += v.x * v.x + v.y * v.y + v.z * v.z + v.w * v.w;
    }
#pragma unroll
    for (int o = 1; o < 64; o <<= 1) {
        ls += __shfl_xor(ls, o);
        lq += __shfl_xor(lq, o);
    }
    __shared__ float red[8];
    int lane = threadIdx.x & 63, w = threadIdx.x >> 6;
    if (lane == 0) { red[w * 2] = ls; red[w * 2 + 1] = lq; }
    __syncthreads();
    if (threadIdx.x == 0) {
        atomicAdd(&stats[0], red[0] + red[2] + red[4] + red[6]);
        atomicAdd(&stats[1], red[1] + red[3] + red[5] + red[7]);
    }
}

// ---------------------------------------------------------------------------
// h = (h - mu) * scale * g[k] + beta[k], in place; mu/scale computed inline
__global__ void normalize_kernel(float* __restrict__ h, const float* __restrict__ g,
                                 const float* __restrict__ beta, const float* __restrict__ stats)
{
    float invM = 1.f / ((float)N_NODES * 256.f);
    float mu = stats[0] * invM;
    float var = stats[1] * invM - mu * mu;
    float sc = rsqrtf(var + EPSN);
    int stride = gridDim.x * blockDim.x;
    int total = N_NODES * 64;      // float4 count
    for (int i = blockIdx.x * blockDim.x + threadIdx.x; i < total; i += stride) {
        float4 v = ((float4*)h)[i];
        int k = (i & 63) * 4;
        float4 gv = *(const float4*)&g[k];
        float4 bv = *(const float4*)&beta[k];
        v.x = (v.x - mu) * sc * gv.x + bv.x;
        v.y = (v.y - mu) * sc * gv.y + bv.y;
        v.z = (v.z - mu) * sc * gv.z + bv.z;
        v.w = (v.w - mu) * sc * gv.w + bv.w;
        ((float4*)h)[i] = v;
    }
}

// ---------------------------------------------------------------------------
extern "C" void kernel_launch(void* const* d_in, const int* in_sizes, int n_in,
                              void* d_out, int out_size, void* d_ws, size_t ws_size,
                              hipStream_t stream)
{
    (void)in_sizes; (void)n_in; (void)out_size; (void)ws_size;
    const float* x     = (const float*)d_in[0];
    const int*   eidx  = (const int*)d_in[1];
    const float* ea    = (const float*)d_in[2];
    const float* W_in  = (const float*)d_in[3];
    const float* b_in  = (const float*)d_in[4];
    const float* W_out = (const float*)d_in[5];
    const float* b_out = (const float*)d_in[6];
    const float* Wl[2]  = {(const float*)d_in[7],  (const float*)d_in[16]};
    const float* bl[2]  = {(const float*)d_in[8],  (const float*)d_in[17]};
    const float* Wr[2]  = {(const float*)d_in[9],  (const float*)d_in[18]};
    const float* br[2]  = {(const float*)d_in[10], (const float*)d_in[19]};
    const float* We[2]  = {(const float*)d_in[11], (const float*)d_in[20]};
    const float* att[2] = {(const float*)d_in[12], (const float*)d_in[21]};
    const float* bias[2]= {(const float*)d_in[13], (const float*)d_in[22]};
    const float* g[2]   = {(const float*)d_in[14], (const float*)d_in[23]};
    const float* beta[2]= {(const float*)d_in[15], (const float*)d_in[24]};

    // workspace layout (~127 MB)
    char* p = (char*)d_ws;
    auto take = [&](size_t bytes) -> char* {
        char* r = p;
        p += (bytes + 255) & ~(size_t)255;
        return r;
    };
    int*   counts  = (int*)take((size_t)N_NODES * 4);
    int*   cursors = (int*)take((size_t)N_NODES * 4);
    float* ea_acc  = (float*)take(32 * 4);
    float* stats   = (float*)take(8 * 4);
    size_t zero_bytes = (size_t)(p - (char*)d_ws);
    int*   offsets = (int*)take((size_t)(N_NODES + 1) * 4);
    int*   s_src   = (int*)take((size_t)E_EDGES * 4);
    int*   s_dst   = (int*)take((size_t)E_EDGES * 4);
    int*   s_eid   = (int*)take((size_t)E_EDGES * 4);
    float* eemean  = (float*)take(512 * 4);
    ushortT* WtIn  = (ushortT*)take((size_t)256 * 384 * 2);
    ushortT* WtLR0 = (ushortT*)take((size_t)512 * 256 * 2);
    ushortT* WtLR1 = (ushortT*)take((size_t)512 * 256 * 2);
    ushortT* WtOut = (ushortT*)take((size_t)256 * 256 * 2);
    ushortT* Wet0  = (ushortT*)take((size_t)256 * 32 * 2);
    ushortT* Wet1  = (ushortT*)take((size_t)256 * 32 * 2);
    float* fb0     = (float*)take(512 * 4);
    float* fb1     = (float*)take(512 * 4);
    ushortT* xlr   = (ushortT*)take((size_t)N_NODES * 512 * 2);
    float* h       = (float*)take((size_t)N_NODES * 256 * 4);
    float* logits  = (float*)take((size_t)E_EDGES * 4 * 4);

    const ushortT* WtLR[2] = {WtLR0, WtLR1};
    const ushortT* Wet[2] = {Wet0, Wet1};
    const float* fb[2] = {fb0, fb1};

    const int* srcv = eidx;
    const int* dstv = eidx + E_EDGES;

    hipMemsetAsync(d_ws, 0, zero_bytes, stream);

    prep_kernel<<<1024, 256, 0, stream>>>(ea, ea_acc, dstv, counts);
    scan_eemean_kernel<<<1, 1024, 0, stream>>>(counts, offsets, ea_acc, We[0], We[1],
                                               eemean, 1.0f / (float)E_EDGES);
    scatter_kernel<<<1024, 256, 0, stream>>>(srcv, dstv, offsets, cursors,
                                             s_src, s_dst, s_eid, E_EDGES);
    transpose_all_kernel<<<dim3(8, 12, 8), 256, 0, stream>>>(
        W_in, Wl[0], Wr[0], Wl[1], Wr[1], W_out, We[0], We[1],
        bl[0], br[0], bl[1], br[1],
        WtIn, WtLR0, WtLR1, WtOut, Wet0, Wet1, fb0, fb1);

    // h0 = relu(x @ W_in + b_in), fp32
    mfma_gemm_kernel<<<dim3(391, 2), 256, 0, stream>>>(x, WtIn, b_in, h, nullptr, 384, 256, 1);

    for (int l = 0; l < 2; ++l) {
        // fused [xl|xr] = h @ [Wl|Wr] + [bl|br], bf16 packed
        mfma_gemm_kernel<<<dim3(391, 4), 256, 0, stream>>>(h, WtLR[l], fb[l], nullptr, xlr,
                                                           256, 512, 0);
        edge_logits_kernel<<<E_EDGES / 256, 256, 0, stream>>>(ea, s_eid, s_src, s_dst,
                                                              Wet[l], att[l], xlr, logits);
        edge_attn_kernel<<<N_NODES / 4, 256, 0, stream>>>(s_src, offsets, logits,
                                                          att[l], bias[l], eemean + l * 256,
                                                          xlr, h);
        stats_kernel<<<2048, 256, 0, stream>>>(h, stats + l * 4);
        normalize_kernel<<<2048, 256, 0, stream>>>(h, g[l], beta[l], stats + l * 4);
    }
    // out = h @ W_out + b_out, fp32
    mfma_gemm_kernel<<<dim3(391, 2), 256, 0, stream>>>(h, WtOut, b_out, (float*)d_out, nullptr,
                                                       256, 256, 0);
}